// Round 1
// baseline (930.488 us; speedup 1.0000x reference)
//
#include <hip/hip_runtime.h>
#include <math.h>

// ---------------- problem constants ----------------
#define NIMG   8
#define NA     15
#define GH     100
#define GW     100
#define HW     10000
#define HWA    150000      // NA*HW
#define SLICE  18750       // HWA/8
#define PRE    2000
#define POST   1000
#define CAP    8192
#define NBINS  2048
#define BBOX_CLIP_F 4.135166556742356f
#define IMGSZ  1600.0f

// ---------------- workspace layout (bytes) ----------------
#define WS_HIST   0u            // u32 [8][2048]   65536
#define WS_CNT    65536u        // u32 [8]         32
#define WS_BSTAR  65568u        // u32 [8]         32
#define WS_CAND   65600u        // u64 [8][8192]   524288
#define WS_ZEND   589888u       // end of zeroed region
#define WS_SCORES 589888u       // f32 [8][150000] 4800000
#define WS_TOPB   5389888u      // f32 [8][2000][4]
#define WS_TOPS   5645888u      // f32 [8][2000]
#define WS_MASK   5709888u      // u64 [8][2000][32]

// Correctly-rounded f32 exp via double, feeding an IEEE f32 add/div chain.
// Models CPU-reference sigmoid: t = expf(-x); s = 1/(1+t), with expf ~correctly rounded.
__device__ __forceinline__ float ref_exp_f32(float x) {
    return (float)exp((double)x);
}
__device__ __forceinline__ float ref_sigmoid(float x) {
    float t = ref_exp_f32(-x);
    return __fdiv_rn(1.0f, __fadd_rn(1.0f, t));
}

// ---- K1: sigmoid scores (cached in obj layout) + 2048-bin histogram ----
__global__ void k_score_hist(const float* __restrict__ obj,
                             float* __restrict__ scores,
                             unsigned* __restrict__ hist) {
    __shared__ unsigned lh[NBINS];
    const int n = blockIdx.y, slice = blockIdx.x, tid = threadIdx.x;
    for (int t = tid; t < NBINS; t += 1024) lh[t] = 0u;
    __syncthreads();
    const float* op = obj + (size_t)n * HWA;
    float* sp = scores + (size_t)n * HWA;
    const int base = slice * SLICE;
    for (int t = tid; t < SLICE; t += 1024) {
        int e = base + t;
        float s = ref_sigmoid(op[e]);
        sp[e] = s;
        unsigned b = __float_as_uint(s) >> 19;
        if (b > NBINS - 1) b = NBINS - 1;
        atomicAdd(&lh[b], 1u);
    }
    __syncthreads();
    unsigned* gh = hist + n * NBINS;
    for (int t = tid; t < NBINS; t += 1024)
        if (lh[t]) atomicAdd(&gh[t], lh[t]);
}

// ---- K2: find cutoff bucket per image (cumulative-from-top >= PRE) ----
__global__ void k_bstar(const unsigned* __restrict__ hist,
                        unsigned* __restrict__ bstar) {
    if (threadIdx.x != 0) return;
    const int n = blockIdx.x;
    const unsigned* gh = hist + n * NBINS;
    unsigned cum = 0; int b = NBINS - 1;
    for (; b >= 0; --b) { cum += gh[b]; if (cum >= PRE) break; }
    if (b < 0) b = 0;
    bstar[n] = (unsigned)b;
}

// ---- K3: compact candidates (bucket >= cutoff) into 64-bit sort keys ----
// key = (score_bits << 32) | (0xFFFFFFFF - j)  ->  desc sort = score desc, index asc
__global__ void k_compact(const float* __restrict__ scores,
                          const unsigned* __restrict__ bstar,
                          unsigned long long* __restrict__ cand,
                          unsigned* __restrict__ cnt) {
    const int n = blockIdx.y, slice = blockIdx.x, tid = threadIdx.x;
    const unsigned bs = bstar[n];
    const float* sp = scores + (size_t)n * HWA;
    unsigned long long* cp = cand + (size_t)n * CAP;
    const int base = slice * SLICE;
    for (int t = tid; t < SLICE; t += 1024) {
        int e = base + t;                     // obj layout: e = a*HW + hw
        unsigned sb = __float_as_uint(sp[e]);
        unsigned b = sb >> 19;
        if (b > NBINS - 1) b = NBINS - 1;
        if (b >= bs) {
            unsigned j = (unsigned)((e % HW) * NA + e / HW);  // flat anchor index
            unsigned pos = atomicAdd(&cnt[n], 1u);
            if (pos < CAP)
                cp[pos] = ((unsigned long long)sb << 32) |
                          (unsigned long long)(0xFFFFFFFFu - j);
        }
    }
}

// ---- K4: per-image bitonic sort (8192, desc) + decode top-2000 boxes ----
__global__ void k_sort_decode(const unsigned long long* __restrict__ cand,
                              const float* __restrict__ deltas,
                              float* __restrict__ topb,
                              float* __restrict__ tops) {
    __shared__ unsigned long long sk[CAP];     // 64 KB
    const int n = blockIdx.x, tid = threadIdx.x;
    const unsigned long long* cp = cand + (size_t)n * CAP;
    for (int t = tid; t < CAP; t += 1024) sk[t] = cp[t];
    __syncthreads();
    for (int k = 2; k <= CAP; k <<= 1) {
        for (int j = k >> 1; j > 0; j >>= 1) {
            for (int t = tid; t < CAP; t += 1024) {
                int ixj = t ^ j;
                if (ixj > t) {
                    unsigned long long a = sk[t], b = sk[ixj];
                    bool up = (t & k) == 0;
                    if (up ? (a < b) : (a > b)) { sk[t] = b; sk[ixj] = a; }
                }
            }
            __syncthreads();
        }
    }
    // decode the top PRE entries (count >= PRE guaranteed by cutoff choice)
    const float* dp = deltas + (size_t)n * (NA * 4 * HW);
    for (int t = tid; t < PRE; t += 1024) {
        unsigned long long key = sk[t];
        unsigned sb = (unsigned)(key >> 32);
        unsigned j  = 0xFFFFFFFFu - (unsigned)(key & 0xFFFFFFFFull);
        float s = __uint_as_float(sb);
        int a  = (int)(j % NA), hw = (int)(j / NA);
        int gy = hw / GW, gx = hw % GW;
        int r  = a / 5, si = a % 5;
        // cell anchor, bit-exact vs reference f32 math
        float ratio = (r == 0) ? 0.5f : ((r == 1) ? 1.0f : 2.0f);
        float hr = __fsqrt_rn(ratio);
        float wr = __fdiv_rn(1.0f, hr);
        float scale = (float)(32 << si);
        float wsz = __fmul_rn(wr, scale);
        float hsz = __fmul_rn(hr, scale);
        float bx1 = rintf(__fmul_rn(-wsz, 0.5f));
        float by1 = rintf(__fmul_rn(-hsz, 0.5f));
        float bx2 = rintf(__fmul_rn(wsz, 0.5f));
        float by2 = rintf(__fmul_rn(hsz, 0.5f));
        float sx = (float)(gx * 16), sy = (float)(gy * 16);
        float ax1 = sx + bx1, ay1 = sy + by1, ax2 = sx + bx2, ay2 = sy + by2;
        float wa = __fsub_rn(ax2, ax1), ha = __fsub_rn(ay2, ay1);
        float cxa = __fadd_rn(ax1, __fmul_rn(0.5f, wa));
        float cya = __fadd_rn(ay1, __fmul_rn(0.5f, ha));
        // deltas gather: [n, a, c, gy, gx]
        int off = gy * GW + gx;
        float dx = dp[(a * 4 + 0) * HW + off];
        float dy = dp[(a * 4 + 1) * HW + off];
        float dw = fminf(dp[(a * 4 + 2) * HW + off], BBOX_CLIP_F);
        float dh = fminf(dp[(a * 4 + 3) * HW + off], BBOX_CLIP_F);
        float cx = __fadd_rn(__fmul_rn(dx, wa), cxa);
        float cy = __fadd_rn(__fmul_rn(dy, ha), cya);
        float bw = __fmul_rn(ref_exp_f32(dw), wa);
        float bh = __fmul_rn(ref_exp_f32(dh), ha);
        float hbw = __fmul_rn(0.5f, bw), hbh = __fmul_rn(0.5f, bh);
        float x1 = fminf(fmaxf(__fsub_rn(cx, hbw), 0.0f), IMGSZ);
        float y1 = fminf(fmaxf(__fsub_rn(cy, hbh), 0.0f), IMGSZ);
        float x2 = fminf(fmaxf(__fadd_rn(cx, hbw), 0.0f), IMGSZ);
        float y2 = fminf(fmaxf(__fadd_rn(cy, hbh), 0.0f), IMGSZ);
        float* tb = topb + ((size_t)n * PRE + t) * 4;
        tb[0] = x1; tb[1] = y1; tb[2] = x2; tb[3] = y2;
        bool valid = (__fsub_rn(x2, x1) >= 1e-3f) && (__fsub_rn(y2, y1) >= 1e-3f);
        tops[(size_t)n * PRE + t] = valid ? s : -1.0f;
    }
}

// ---- K5: 2000x2000 IoU suppression bitmask (bit j of row i: j>i && iou>0.7) ----
__global__ void k_iou(const float* __restrict__ topb,
                      unsigned long long* __restrict__ mask) {
    __shared__ float X1[PRE], Y1[PRE], X2[PRE], Y2[PRE];   // SoA: conflict-free
    const int n = blockIdx.y, rowblk = blockIdx.x, tid = threadIdx.x;
    const float* tb = topb + (size_t)n * PRE * 4;
    for (int t = tid; t < PRE; t += 256) {
        X1[t] = tb[t * 4 + 0]; Y1[t] = tb[t * 4 + 1];
        X2[t] = tb[t * 4 + 2]; Y2[t] = tb[t * 4 + 3];
    }
    __syncthreads();
    const int wave = tid >> 6, lane = tid & 63;
    for (int rr = 0; rr < 8; ++rr) {
        int i = rowblk * 32 + wave * 8 + rr;
        if (i >= PRE) break;
        float bi0 = X1[i], bi1 = Y1[i], bi2 = X2[i], bi3 = Y2[i];
        float ai = __fmul_rn(__fsub_rn(bi2, bi0), __fsub_rn(bi3, bi1));
        unsigned long long* mrow = mask + ((size_t)n * PRE + i) * 32;
        for (int c = 0; c < 32; ++c) {
            int j = c * 64 + lane;
            bool bit = false;
            if (j < PRE && j > i) {
                float bj0 = X1[j], bj1 = Y1[j], bj2 = X2[j], bj3 = Y2[j];
                float aj = __fmul_rn(__fsub_rn(bj2, bj0), __fsub_rn(bj3, bj1));
                float ltx = fmaxf(bi0, bj0), lty = fmaxf(bi1, bj1);
                float rbx = fminf(bi2, bj2), rby = fminf(bi3, bj3);
                float ww = fmaxf(__fsub_rn(rbx, ltx), 0.0f);
                float hh = fmaxf(__fsub_rn(rby, lty), 0.0f);
                float inter = __fmul_rn(ww, hh);
                float denom = __fadd_rn(__fsub_rn(__fadd_rn(ai, aj), inter), 1e-6f);
                bit = __fdiv_rn(inter, denom) > 0.7f;
            }
            unsigned long long m = __ballot(bit);
            if (lane == 0) mrow[c] = m;
        }
    }
}

// ---- K6: serial greedy NMS (one wave per image) + output write ----
__global__ void k_nms_out(const float* __restrict__ topb,
                          const float* __restrict__ tops,
                          const unsigned long long* __restrict__ mask,
                          float* __restrict__ out) {
    __shared__ unsigned char  lvalid[PRE];
    __shared__ unsigned short kept[PRE];
    __shared__ int cnt;
    const int n = blockIdx.x, tid = threadIdx.x;
    const float* sp = tops + (size_t)n * PRE;
    for (int t = tid; t < PRE; t += 256) lvalid[t] = (sp[t] > -0.5f) ? 1 : 0;
    if (tid == 0) cnt = 0;
    __syncthreads();
    if (tid < 64) {
        const int lane = tid;
        const unsigned long long* mb = mask + (size_t)n * PRE * 32;
        unsigned long long remv = 0ull;                      // lane l (<32) owns chunk l
        unsigned long long nxt = (lane < 32) ? mb[lane] : 0ull;
        int kc = 0;
        for (int i = 0; i < PRE; ++i) {
            unsigned long long cur = nxt;
            if (i + 1 < PRE && lane < 32) nxt = mb[(size_t)(i + 1) * 32 + lane];
            int ch = i >> 6;
            unsigned long long r = __shfl(remv, ch);         // broadcast chunk
            bool keep = lvalid[i] && !((r >> (i & 63)) & 1ull);  // wave-uniform
            if (keep) {
                if (lane < 32) remv |= cur;
                if (lane == 0) kept[kc] = (unsigned short)i;
                ++kc;
            }
        }
        if (lane == 0) cnt = kc;
    }
    __syncthreads();
    const int kc = (cnt < POST) ? cnt : POST;
    for (int r = tid; r < POST; r += 256) {
        float o0 = 0.f, o1 = 0.f, o2 = 0.f, o3 = 0.f, o4 = 0.f;
        if (r < kc) {
            int i = kept[r];
            const float* tb = topb + ((size_t)n * PRE + i) * 4;
            o0 = tb[0]; o1 = tb[1]; o2 = tb[2]; o3 = tb[3]; o4 = sp[i];
        }
        float* op = out + ((size_t)n * POST + r) * 5;
        op[0] = o0; op[1] = o1; op[2] = o2; op[3] = o3; op[4] = o4;
    }
}

extern "C" void kernel_launch(void* const* d_in, const int* in_sizes, int n_in,
                              void* d_out, int out_size, void* d_ws, size_t ws_size,
                              hipStream_t stream) {
    const float* obj    = (const float*)d_in[0];   // [8,15,100,100]
    const float* deltas = (const float*)d_in[1];   // [8,60,100,100]
    float* out = (float*)d_out;                    // [8,1000,5]
    char* ws = (char*)d_ws;

    unsigned*            hist  = (unsigned*)(ws + WS_HIST);
    unsigned*            cnt   = (unsigned*)(ws + WS_CNT);
    unsigned*            bstar = (unsigned*)(ws + WS_BSTAR);
    unsigned long long*  cand  = (unsigned long long*)(ws + WS_CAND);
    float*               scrs  = (float*)(ws + WS_SCORES);
    float*               topb  = (float*)(ws + WS_TOPB);
    float*               tops  = (float*)(ws + WS_TOPS);
    unsigned long long*  mask  = (unsigned long long*)(ws + WS_MASK);

    hipMemsetAsync(ws, 0, WS_ZEND, stream);
    k_score_hist <<<dim3(8, NIMG), 1024, 0, stream>>>(obj, scrs, hist);
    k_bstar      <<<NIMG, 64, 0, stream>>>(hist, bstar);
    k_compact    <<<dim3(8, NIMG), 1024, 0, stream>>>(scrs, bstar, cand, cnt);
    k_sort_decode<<<NIMG, 1024, 0, stream>>>(cand, deltas, topb, tops);
    k_iou        <<<dim3(63, NIMG), 256, 0, stream>>>(topb, mask);
    k_nms_out    <<<NIMG, 256, 0, stream>>>(topb, tops, mask, out);
}

// Round 2
// 646.271 us; speedup vs baseline: 1.4398x; 1.4398x over previous
//
#include <hip/hip_runtime.h>
#include <math.h>

// ---------------- problem constants ----------------
#define NIMG   8
#define NA     15
#define GH     100
#define GW     100
#define HW     10000
#define HWA    150000      // NA*HW
#define SLICE  18750       // HWA/8
#define PRE    2000
#define POST   1000
#define CAP    8192
#define NBINS  2048
#define BBOX_CLIP_F 4.135166556742356f
#define IMGSZ  1600.0f

// ---------------- workspace layout (bytes) ----------------
#define WS_HIST   0u            // u32 [8][2048]   65536
#define WS_CNT    65536u        // u32 [8]         32
#define WS_BSTAR  65568u        // u32 [8]         32
#define WS_CAND   65600u        // u64 [8][8192]   524288
#define WS_ZEND   589888u       // end of zeroed region
#define WS_SCORES 589888u       // f32 [8][150000] 4800000
#define WS_TOPB   5389888u      // f32 [8][2000][4]
#define WS_TOPS   5645888u      // f32 [8][2000]
#define WS_MASK   5709888u      // u64 [8][2000][32]

// Correctly-rounded f32 exp via double, feeding an IEEE f32 add/div chain.
// Models CPU-reference sigmoid: t = expf(-x); s = 1/(1+t). VERIFIED bit-exact R1.
__device__ __forceinline__ float ref_exp_f32(float x) {
    return (float)exp((double)x);
}
__device__ __forceinline__ float ref_sigmoid(float x) {
    float t = ref_exp_f32(-x);
    return __fdiv_rn(1.0f, __fadd_rn(1.0f, t));
}

// ---- K1: sigmoid scores (cached in obj layout) + 2048-bin histogram ----
__global__ void k_score_hist(const float* __restrict__ obj,
                             float* __restrict__ scores,
                             unsigned* __restrict__ hist) {
    __shared__ unsigned lh[NBINS];
    const int n = blockIdx.y, slice = blockIdx.x, tid = threadIdx.x;
    for (int t = tid; t < NBINS; t += 1024) lh[t] = 0u;
    __syncthreads();
    const float* op = obj + (size_t)n * HWA;
    float* sp = scores + (size_t)n * HWA;
    const int base = slice * SLICE;
    for (int t = tid; t < SLICE; t += 1024) {
        int e = base + t;
        float s = ref_sigmoid(op[e]);
        sp[e] = s;
        unsigned b = __float_as_uint(s) >> 19;
        if (b > NBINS - 1) b = NBINS - 1;
        atomicAdd(&lh[b], 1u);
    }
    __syncthreads();
    unsigned* gh = hist + n * NBINS;
    for (int t = tid; t < NBINS; t += 1024)
        if (lh[t]) atomicAdd(&gh[t], lh[t]);
}

// ---- K2: cutoff bucket per image, wave-parallel suffix sum ----
// b* = max{b : sum_{x>=b} hist[x] >= PRE}  (0 if total < PRE)
__global__ void k_bstar(const unsigned* __restrict__ hist,
                        unsigned* __restrict__ bstar) {
    const int n = blockIdx.x, lane = threadIdx.x;   // 64 threads
    const unsigned* gh = hist + n * NBINS;
    unsigned v[32];
    unsigned S = 0;
    #pragma unroll
    for (int t = 0; t < 32; ++t) { v[t] = gh[lane * 32 + t]; S += v[t]; }
    // suffix sum across lanes: T_l = sum_{m>=l} S_m
    unsigned T = S;
    #pragma unroll
    for (int d = 1; d < 64; d <<= 1) {
        unsigned u = __shfl_down(T, d);
        if (lane + d < 64) T += u;
    }
    unsigned Tn = T - S;                 // sum over lanes > l
    int bestt = -1;
    unsigned W = 0;
    #pragma unroll
    for (int t = 31; t >= 0; --t) {
        W += v[t];
        if (bestt < 0 && W + Tn >= PRE) bestt = t;
    }
    unsigned long long hm = __ballot(bestt >= 0);
    if (hm == 0ull) {
        if (lane == 0) bstar[n] = 0u;
    } else {
        int hl = 63 - __builtin_clzll(hm);
        if (lane == hl) bstar[n] = (unsigned)(lane * 32 + bestt);
    }
}

// ---- K3: compact candidates (bucket >= cutoff) into 64-bit sort keys ----
// key = (score_bits << 32) | (0xFFFFFFFF - j)  ->  desc sort = score desc, index asc
__global__ void k_compact(const float* __restrict__ scores,
                          const unsigned* __restrict__ bstar,
                          unsigned long long* __restrict__ cand,
                          unsigned* __restrict__ cnt) {
    const int n = blockIdx.y, slice = blockIdx.x, tid = threadIdx.x;
    const unsigned bs = bstar[n];
    const float* sp = scores + (size_t)n * HWA;
    unsigned long long* cp = cand + (size_t)n * CAP;
    const int base = slice * SLICE;
    for (int t = tid; t < SLICE; t += 1024) {
        int e = base + t;                     // obj layout: e = a*HW + hw
        unsigned sb = __float_as_uint(sp[e]);
        unsigned b = sb >> 19;
        if (b > NBINS - 1) b = NBINS - 1;
        if (b >= bs) {
            unsigned j = (unsigned)((e % HW) * NA + e / HW);  // flat anchor index
            unsigned pos = atomicAdd(&cnt[n], 1u);
            if (pos < CAP)
                cp[pos] = ((unsigned long long)sb << 32) |
                          (unsigned long long)(0xFFFFFFFFu - j);
        }
    }
}

// ---- K4: per-image bitonic sort (8192, desc) + decode top-2000 boxes ----
__global__ void k_sort_decode(const unsigned long long* __restrict__ cand,
                              const float* __restrict__ deltas,
                              float* __restrict__ topb,
                              float* __restrict__ tops) {
    __shared__ unsigned long long sk[CAP];     // 64 KB
    const int n = blockIdx.x, tid = threadIdx.x;
    const unsigned long long* cp = cand + (size_t)n * CAP;
    for (int t = tid; t < CAP; t += 1024) sk[t] = cp[t];
    __syncthreads();
    for (int k = 2; k <= CAP; k <<= 1) {
        for (int j = k >> 1; j > 0; j >>= 1) {
            for (int t = tid; t < CAP; t += 1024) {
                int ixj = t ^ j;
                if (ixj > t) {
                    unsigned long long a = sk[t], b = sk[ixj];
                    bool up = (t & k) == 0;
                    if (up ? (a < b) : (a > b)) { sk[t] = b; sk[ixj] = a; }
                }
            }
            __syncthreads();
        }
    }
    // decode the top PRE entries (count >= PRE guaranteed by cutoff choice)
    const float* dp = deltas + (size_t)n * (NA * 4 * HW);
    for (int t = tid; t < PRE; t += 1024) {
        unsigned long long key = sk[t];
        unsigned sb = (unsigned)(key >> 32);
        unsigned j  = 0xFFFFFFFFu - (unsigned)(key & 0xFFFFFFFFull);
        float s = __uint_as_float(sb);
        int a  = (int)(j % NA), hw = (int)(j / NA);
        int gy = hw / GW, gx = hw % GW;
        int r  = a / 5, si = a % 5;
        // cell anchor, bit-exact vs reference f32 math
        float ratio = (r == 0) ? 0.5f : ((r == 1) ? 1.0f : 2.0f);
        float hr = __fsqrt_rn(ratio);
        float wr = __fdiv_rn(1.0f, hr);
        float scale = (float)(32 << si);
        float wsz = __fmul_rn(wr, scale);
        float hsz = __fmul_rn(hr, scale);
        float bx1 = rintf(__fmul_rn(-wsz, 0.5f));
        float by1 = rintf(__fmul_rn(-hsz, 0.5f));
        float bx2 = rintf(__fmul_rn(wsz, 0.5f));
        float by2 = rintf(__fmul_rn(hsz, 0.5f));
        float sx = (float)(gx * 16), sy = (float)(gy * 16);
        float ax1 = sx + bx1, ay1 = sy + by1, ax2 = sx + bx2, ay2 = sy + by2;
        float wa = __fsub_rn(ax2, ax1), ha = __fsub_rn(ay2, ay1);
        float cxa = __fadd_rn(ax1, __fmul_rn(0.5f, wa));
        float cya = __fadd_rn(ay1, __fmul_rn(0.5f, ha));
        // deltas gather: [n, a, c, gy, gx]
        int off = gy * GW + gx;
        float dx = dp[(a * 4 + 0) * HW + off];
        float dy = dp[(a * 4 + 1) * HW + off];
        float dw = fminf(dp[(a * 4 + 2) * HW + off], BBOX_CLIP_F);
        float dh = fminf(dp[(a * 4 + 3) * HW + off], BBOX_CLIP_F);
        float cx = __fadd_rn(__fmul_rn(dx, wa), cxa);
        float cy = __fadd_rn(__fmul_rn(dy, ha), cya);
        float bw = __fmul_rn(ref_exp_f32(dw), wa);
        float bh = __fmul_rn(ref_exp_f32(dh), ha);
        float hbw = __fmul_rn(0.5f, bw), hbh = __fmul_rn(0.5f, bh);
        float x1 = fminf(fmaxf(__fsub_rn(cx, hbw), 0.0f), IMGSZ);
        float y1 = fminf(fmaxf(__fsub_rn(cy, hbh), 0.0f), IMGSZ);
        float x2 = fminf(fmaxf(__fadd_rn(cx, hbw), 0.0f), IMGSZ);
        float y2 = fminf(fmaxf(__fadd_rn(cy, hbh), 0.0f), IMGSZ);
        float* tb = topb + ((size_t)n * PRE + t) * 4;
        tb[0] = x1; tb[1] = y1; tb[2] = x2; tb[3] = y2;
        bool valid = (__fsub_rn(x2, x1) >= 1e-3f) && (__fsub_rn(y2, y1) >= 1e-3f);
        tops[(size_t)n * PRE + t] = valid ? s : -1.0f;
    }
}

// ---- K5: 2000x2000 IoU suppression bitmask (bit j of row i: j>i && iou>0.7) ----
__global__ void k_iou(const float* __restrict__ topb,
                      unsigned long long* __restrict__ mask) {
    __shared__ float X1[PRE], Y1[PRE], X2[PRE], Y2[PRE];   // SoA: conflict-free
    const int n = blockIdx.y, rowblk = blockIdx.x, tid = threadIdx.x;
    const float4* tb4 = (const float4*)(topb + (size_t)n * PRE * 4);
    for (int t = tid; t < PRE; t += 256) {
        float4 b = tb4[t];
        X1[t] = b.x; Y1[t] = b.y; X2[t] = b.z; Y2[t] = b.w;
    }
    __syncthreads();
    const int wave = tid >> 6, lane = tid & 63;
    for (int rr = 0; rr < 8; ++rr) {
        int i = rowblk * 32 + wave * 8 + rr;
        if (i >= PRE) break;
        float bi0 = X1[i], bi1 = Y1[i], bi2 = X2[i], bi3 = Y2[i];
        float ai = __fmul_rn(__fsub_rn(bi2, bi0), __fsub_rn(bi3, bi1));
        unsigned long long* mrow = mask + ((size_t)n * PRE + i) * 32;
        for (int c = 0; c < 32; ++c) {
            int j = c * 64 + lane;
            bool bit = false;
            if (j < PRE && j > i) {
                float bj0 = X1[j], bj1 = Y1[j], bj2 = X2[j], bj3 = Y2[j];
                float aj = __fmul_rn(__fsub_rn(bj2, bj0), __fsub_rn(bj3, bj1));
                float ltx = fmaxf(bi0, bj0), lty = fmaxf(bi1, bj1);
                float rbx = fminf(bi2, bj2), rby = fminf(bi3, bj3);
                float ww = fmaxf(__fsub_rn(rbx, ltx), 0.0f);
                float hh = fmaxf(__fsub_rn(rby, lty), 0.0f);
                float inter = __fmul_rn(ww, hh);
                float denom = __fadd_rn(__fsub_rn(__fadd_rn(ai, aj), inter), 1e-6f);
                bit = __fdiv_rn(inter, denom) > 0.7f;
            }
            unsigned long long m = __ballot(bit);
            if (lane == 0) mrow[c] = m;
        }
    }
}

// ---- K6: greedy NMS, group-of-64 formulation + early exit + output ----
// Critical path per suppressed row: ~6 VALU cyc. Per kept row: one 64b shfl.
// Full remv update batched as 32 independent coalesced loads per half-group.
__global__ void k_nms_out(const float* __restrict__ topb,
                          const float* __restrict__ tops,
                          const unsigned long long* __restrict__ mask,
                          float* __restrict__ out) {
    __shared__ unsigned short kept[POST];
    __shared__ int cnt;
    const int n = blockIdx.x, tid = threadIdx.x;   // 256 threads
    const float* sp = tops + (size_t)n * PRE;
    if (tid < 64) {
        const int lane = tid;
        const unsigned long long* mb = mask + (size_t)n * PRE * 32;
        // valid bitmaps: lane w (w<32) holds 64-bit validity of rows [w*64, w*64+64)
        unsigned long long vbit = 0ull;
        for (int w = 0; w < 32; ++w) {
            int i = w * 64 + lane;
            bool v = (i < PRE) && (sp[i] > -0.5f);
            unsigned long long m = __ballot(v);
            if (lane == w) vbit = m;
        }
        unsigned long long remv = 0ull;   // lane l (<32) owns suppression chunk l
        int kc = 0;
        // prefetch group-0 row chunks: row=lane, chunk 0
        unsigned long long r = mb[(size_t)lane * 32 + 0];
        for (int g = 0; g < 32 && kc < POST; ++g) {
            const int base = g * 64;
            const int glen = (PRE - base < 64) ? (PRE - base) : 64;
            unsigned long long cc = __shfl(remv, g);
            unsigned long long vb = __shfl(vbit, g);
            unsigned long long rr = r;
            if (g + 1 < 32) {   // prefetch next group's row chunks
                int row = (g + 1) * 64 + lane;
                r = (row < PRE) ? mb[(size_t)row * 32 + (g + 1)] : 0ull;
            }
            unsigned long long kb = 0ull;
            for (int jj = 0; jj < glen; ++jj) {
                unsigned long long bit = 1ull << jj;
                if ((vb & bit) && !(cc & bit)) {
                    cc |= __shfl(rr, jj);
                    kb |= bit;
                    if (lane == 0) kept[kc] = (unsigned short)(base + jj);
                    ++kc;
                    if (kc == POST) break;
                }
            }
            // fold kept rows into remv: two batches of 32 independent loads
            if (kc < POST && kb) {
                #pragma unroll
                for (int half = 0; half < 2; ++half) {
                    unsigned long long acc = 0ull;
                    unsigned long long v0[32];
                    #pragma unroll
                    for (int t = 0; t < 32; ++t) {
                        int jj = half * 32 + t;
                        bool need = ((kb >> jj) & 1ull) && (lane < 32) &&
                                    (base + jj < PRE);
                        v0[t] = need ? mb[(size_t)(base + jj) * 32 + lane] : 0ull;
                    }
                    #pragma unroll
                    for (int t = 0; t < 32; ++t) acc |= v0[t];
                    remv |= acc;
                }
            }
        }
        if (lane == 0) cnt = kc;
    }
    __syncthreads();
    const int kc = (cnt < POST) ? cnt : POST;
    for (int rI = tid; rI < POST; rI += 256) {
        float o0 = 0.f, o1 = 0.f, o2 = 0.f, o3 = 0.f, o4 = 0.f;
        if (rI < kc) {
            int i = kept[rI];
            const float* tb = topb + ((size_t)n * PRE + i) * 4;
            o0 = tb[0]; o1 = tb[1]; o2 = tb[2]; o3 = tb[3]; o4 = sp[i];
        }
        float* op = out + ((size_t)n * POST + rI) * 5;
        op[0] = o0; op[1] = o1; op[2] = o2; op[3] = o3; op[4] = o4;
    }
}

extern "C" void kernel_launch(void* const* d_in, const int* in_sizes, int n_in,
                              void* d_out, int out_size, void* d_ws, size_t ws_size,
                              hipStream_t stream) {
    const float* obj    = (const float*)d_in[0];   // [8,15,100,100]
    const float* deltas = (const float*)d_in[1];   // [8,60,100,100]
    float* out = (float*)d_out;                    // [8,1000,5]
    char* ws = (char*)d_ws;

    unsigned*            hist  = (unsigned*)(ws + WS_HIST);
    unsigned*            cnt   = (unsigned*)(ws + WS_CNT);
    unsigned*            bstar = (unsigned*)(ws + WS_BSTAR);
    unsigned long long*  cand  = (unsigned long long*)(ws + WS_CAND);
    float*               scrs  = (float*)(ws + WS_SCORES);
    float*               topb  = (float*)(ws + WS_TOPB);
    float*               tops  = (float*)(ws + WS_TOPS);
    unsigned long long*  mask  = (unsigned long long*)(ws + WS_MASK);

    hipMemsetAsync(ws, 0, WS_ZEND, stream);
    k_score_hist <<<dim3(8, NIMG), 1024, 0, stream>>>(obj, scrs, hist);
    k_bstar      <<<NIMG, 64, 0, stream>>>(hist, bstar);
    k_compact    <<<dim3(8, NIMG), 1024, 0, stream>>>(scrs, bstar, cand, cnt);
    k_sort_decode<<<NIMG, 1024, 0, stream>>>(cand, deltas, topb, tops);
    k_iou        <<<dim3(63, NIMG), 256, 0, stream>>>(topb, mask);
    k_nms_out    <<<NIMG, 256, 0, stream>>>(topb, tops, mask, out);
}

// Round 3
// 488.409 us; speedup vs baseline: 1.9051x; 1.3232x over previous
//
#include <hip/hip_runtime.h>
#include <math.h>

// ---------------- problem constants ----------------
#define NIMG   8
#define NA     15
#define GH     100
#define GW     100
#define HW     10000
#define HWA    150000      // NA*HW
#define SLICE  18750       // HWA/8
#define PRE    2000
#define POST   1000
#define CAP    4096        // candidate cap; logit-binning keeps C ~2030 << 4096
#define NBINS  2048
#define BBOX_CLIP_F 4.135166556742356f
#define IMGSZ  1600.0f
#define BINSCALE 170.6666667f   // NBINS / 12 over logit range [-6,6]

// ---------------- workspace layout (bytes) ----------------
#define WS_HIST   0u            // u32 [8][2048]   65536
#define WS_CNT    65536u        // u32 [8]         32
#define WS_BSTAR  65568u        // u32 [8]         32
#define WS_DUMMY  65600u        // u64 [32] zeros  256   (NMS fold padding row)
#define WS_CAND   65856u        // u64 [8][4096]   262144
#define WS_ZEND   328000u       // end of zeroed region
#define WS_TOPB   328000u       // f32 [8][2000][4] 256000
#define WS_TOPS   584000u       // f32 [8][2000]    64000
#define WS_MASK   648000u       // u64 [8][2000][32] 4096000  (end 4744000)

// Correctly-rounded f32 exp via double, feeding an IEEE f32 add/div chain.
// Models CPU-reference sigmoid: t = expf(-x); s = 1/(1+t). VERIFIED bit-exact R1/R2.
__device__ __forceinline__ float ref_exp_f32(float x) {
    return (float)exp((double)x);
}
__device__ __forceinline__ float ref_sigmoid(float x) {
    float t = ref_exp_f32(-x);
    return __fdiv_rn(1.0f, __fadd_rn(1.0f, t));
}

// monotone logit->bin map (must be IDENTICAL in k_hist and k_compact)
__device__ __forceinline__ int logit_bin(float x) {
    int b = (int)floorf(__fmul_rn(__fadd_rn(x, 6.0f), BINSCALE));
    return max(0, min(NBINS - 1, b));
}

// 64-bit wave-uniform broadcast via scalar readlane (cheaper than ds_permute shfl)
__device__ __forceinline__ unsigned long long rl64(unsigned long long v, int l) {
    unsigned lo = (unsigned)__builtin_amdgcn_readlane((int)(unsigned)v, l);
    unsigned hi = (unsigned)__builtin_amdgcn_readlane((int)(unsigned)(v >> 32), l);
    return ((unsigned long long)hi << 32) | (unsigned long long)lo;
}

// ---- K1: logit histogram (2048 bins over [-6,6]) ----
__global__ void k_hist(const float* __restrict__ obj,
                       unsigned* __restrict__ hist) {
    __shared__ unsigned lh[NBINS];
    const int n = blockIdx.y, slice = blockIdx.x, tid = threadIdx.x;
    for (int t = tid; t < NBINS; t += 1024) lh[t] = 0u;
    __syncthreads();
    const float* op = obj + (size_t)n * HWA;
    const int base = slice * SLICE;
    for (int t = tid; t < SLICE; t += 1024) {
        int b = logit_bin(op[base + t]);
        atomicAdd(&lh[b], 1u);
    }
    __syncthreads();
    unsigned* gh = hist + n * NBINS;
    for (int t = tid; t < NBINS; t += 1024)
        if (lh[t]) atomicAdd(&gh[t], lh[t]);
}

// ---- K2: cutoff bucket per image, wave-parallel suffix sum ----
// b* = max{b : sum_{x>=b} hist[x] >= PRE}  (0 if total < PRE)
__global__ void k_bstar(const unsigned* __restrict__ hist,
                        unsigned* __restrict__ bstar) {
    const int n = blockIdx.x, lane = threadIdx.x;   // 64 threads
    const unsigned* gh = hist + n * NBINS;
    unsigned v[32];
    unsigned S = 0;
    #pragma unroll
    for (int t = 0; t < 32; ++t) { v[t] = gh[lane * 32 + t]; S += v[t]; }
    unsigned T = S;
    #pragma unroll
    for (int d = 1; d < 64; d <<= 1) {
        unsigned u = __shfl_down(T, d);
        if (lane + d < 64) T += u;
    }
    unsigned Tn = T - S;                 // sum over lanes > l
    int bestt = -1;
    unsigned W = 0;
    #pragma unroll
    for (int t = 31; t >= 0; --t) {
        W += v[t];
        if (bestt < 0 && W + Tn >= PRE) bestt = t;
    }
    unsigned long long hm = __ballot(bestt >= 0);
    if (hm == 0ull) {
        if (lane == 0) bstar[n] = 0u;
    } else {
        int hl = 63 - __builtin_clzll(hm);
        if (lane == hl) bstar[n] = (unsigned)(lane * 32 + bestt);
    }
}

// ---- K3: compact candidates (bin >= cutoff) into 64-bit sort keys ----
// key = (score_bits << 32) | (0xFFFFFFFF - j)  ->  desc sort = score desc, index asc
__global__ void k_compact(const float* __restrict__ obj,
                          const unsigned* __restrict__ bstar,
                          unsigned long long* __restrict__ cand,
                          unsigned* __restrict__ cnt) {
    const int n = blockIdx.y, slice = blockIdx.x, tid = threadIdx.x;
    const int bs = (int)bstar[n];
    const float* op = obj + (size_t)n * HWA;
    unsigned long long* cp = cand + (size_t)n * CAP;
    const int base = slice * SLICE;
    for (int t = tid; t < SLICE; t += 1024) {
        int e = base + t;                     // obj layout: e = a*HW + hw
        float x = op[e];
        if (logit_bin(x) >= bs) {
            unsigned sb = __float_as_uint(ref_sigmoid(x));
            unsigned j = (unsigned)((e % HW) * NA + e / HW);  // flat anchor index
            unsigned pos = atomicAdd(&cnt[n], 1u);
            if (pos < CAP)
                cp[pos] = ((unsigned long long)sb << 32) |
                          (unsigned long long)(0xFFFFFFFFu - j);
        }
    }
}

// ---- K4: per-image bitonic sort (4096, desc) + decode top-2000 boxes ----
__global__ void k_sort_decode(const unsigned long long* __restrict__ cand,
                              const float* __restrict__ deltas,
                              float* __restrict__ topb,
                              float* __restrict__ tops) {
    __shared__ unsigned long long sk[CAP];     // 32 KB
    const int n = blockIdx.x, tid = threadIdx.x;
    const unsigned long long* cp = cand + (size_t)n * CAP;
    for (int t = tid; t < CAP; t += 1024) sk[t] = cp[t];
    __syncthreads();
    for (int k = 2; k <= CAP; k <<= 1) {
        for (int j = k >> 1; j > 0; j >>= 1) {
            for (int t = tid; t < CAP; t += 1024) {
                int ixj = t ^ j;
                if (ixj > t) {
                    unsigned long long a = sk[t], b = sk[ixj];
                    bool up = (t & k) == 0;
                    if (up ? (a < b) : (a > b)) { sk[t] = b; sk[ixj] = a; }
                }
            }
            __syncthreads();
        }
    }
    // decode the top PRE entries (count >= PRE guaranteed by cutoff choice)
    const float* dp = deltas + (size_t)n * (NA * 4 * HW);
    for (int t = tid; t < PRE; t += 1024) {
        unsigned long long key = sk[t];
        unsigned sb = (unsigned)(key >> 32);
        unsigned j  = 0xFFFFFFFFu - (unsigned)(key & 0xFFFFFFFFull);
        float s = __uint_as_float(sb);
        int a  = (int)(j % NA), hw = (int)(j / NA);
        int gy = hw / GW, gx = hw % GW;
        int r  = a / 5, si = a % 5;
        // cell anchor, bit-exact vs reference f32 math
        float ratio = (r == 0) ? 0.5f : ((r == 1) ? 1.0f : 2.0f);
        float hr = __fsqrt_rn(ratio);
        float wr = __fdiv_rn(1.0f, hr);
        float scale = (float)(32 << si);
        float wsz = __fmul_rn(wr, scale);
        float hsz = __fmul_rn(hr, scale);
        float bx1 = rintf(__fmul_rn(-wsz, 0.5f));
        float by1 = rintf(__fmul_rn(-hsz, 0.5f));
        float bx2 = rintf(__fmul_rn(wsz, 0.5f));
        float by2 = rintf(__fmul_rn(hsz, 0.5f));
        float sx = (float)(gx * 16), sy = (float)(gy * 16);
        float ax1 = sx + bx1, ay1 = sy + by1, ax2 = sx + bx2, ay2 = sy + by2;
        float wa = __fsub_rn(ax2, ax1), ha = __fsub_rn(ay2, ay1);
        float cxa = __fadd_rn(ax1, __fmul_rn(0.5f, wa));
        float cya = __fadd_rn(ay1, __fmul_rn(0.5f, ha));
        int off = gy * GW + gx;
        float dx = dp[(a * 4 + 0) * HW + off];
        float dy = dp[(a * 4 + 1) * HW + off];
        float dw = fminf(dp[(a * 4 + 2) * HW + off], BBOX_CLIP_F);
        float dh = fminf(dp[(a * 4 + 3) * HW + off], BBOX_CLIP_F);
        float cx = __fadd_rn(__fmul_rn(dx, wa), cxa);
        float cy = __fadd_rn(__fmul_rn(dy, ha), cya);
        float bw = __fmul_rn(ref_exp_f32(dw), wa);
        float bh = __fmul_rn(ref_exp_f32(dh), ha);
        float hbw = __fmul_rn(0.5f, bw), hbh = __fmul_rn(0.5f, bh);
        float x1 = fminf(fmaxf(__fsub_rn(cx, hbw), 0.0f), IMGSZ);
        float y1 = fminf(fmaxf(__fsub_rn(cy, hbh), 0.0f), IMGSZ);
        float x2 = fminf(fmaxf(__fadd_rn(cx, hbw), 0.0f), IMGSZ);
        float y2 = fminf(fmaxf(__fadd_rn(cy, hbh), 0.0f), IMGSZ);
        float* tb = topb + ((size_t)n * PRE + t) * 4;
        tb[0] = x1; tb[1] = y1; tb[2] = x2; tb[3] = y2;
        bool valid = (__fsub_rn(x2, x1) >= 1e-3f) && (__fsub_rn(y2, y1) >= 1e-3f);
        tops[(size_t)n * PRE + t] = valid ? s : -1.0f;
    }
}

// ---- K5: 2000x2000 IoU suppression bitmask (bit j of row i: j>i && iou>0.7) ----
__global__ void k_iou(const float* __restrict__ topb,
                      unsigned long long* __restrict__ mask) {
    __shared__ float X1[PRE], Y1[PRE], X2[PRE], Y2[PRE];   // SoA: conflict-free
    const int n = blockIdx.y, rowblk = blockIdx.x, tid = threadIdx.x;
    const float4* tb4 = (const float4*)(topb + (size_t)n * PRE * 4);
    for (int t = tid; t < PRE; t += 256) {
        float4 b = tb4[t];
        X1[t] = b.x; Y1[t] = b.y; X2[t] = b.z; Y2[t] = b.w;
    }
    __syncthreads();
    const int wave = tid >> 6, lane = tid & 63;
    for (int rr = 0; rr < 8; ++rr) {
        int i = rowblk * 32 + wave * 8 + rr;
        if (i >= PRE) break;
        float bi0 = X1[i], bi1 = Y1[i], bi2 = X2[i], bi3 = Y2[i];
        float ai = __fmul_rn(__fsub_rn(bi2, bi0), __fsub_rn(bi3, bi1));
        unsigned long long* mrow = mask + ((size_t)n * PRE + i) * 32;
        for (int c = 0; c < 32; ++c) {
            int j = c * 64 + lane;
            bool bit = false;
            if (j < PRE && j > i) {
                float bj0 = X1[j], bj1 = Y1[j], bj2 = X2[j], bj3 = Y2[j];
                float aj = __fmul_rn(__fsub_rn(bj2, bj0), __fsub_rn(bj3, bj1));
                float ltx = fmaxf(bi0, bj0), lty = fmaxf(bi1, bj1);
                float rbx = fminf(bi2, bj2), rby = fminf(bi3, bj3);
                float ww = fmaxf(__fsub_rn(rbx, ltx), 0.0f);
                float hh = fmaxf(__fsub_rn(rby, lty), 0.0f);
                float inter = __fmul_rn(ww, hh);
                float denom = __fadd_rn(__fsub_rn(__fadd_rn(ai, aj), inter), 1e-6f);
                bit = __fdiv_rn(inter, denom) > 0.7f;
            }
            unsigned long long m = __ballot(bit);
            if (lane == 0) mrow[c] = m;
        }
    }
}

// ---- K6: greedy NMS, group-of-64 + scalar broadcasts + batched fold ----
__global__ void k_nms_out(const float* __restrict__ topb,
                          const float* __restrict__ tops,
                          const unsigned long long* __restrict__ mask,
                          const unsigned long long* __restrict__ dummy,
                          float* __restrict__ out) {
    __shared__ unsigned short kept[POST];
    __shared__ int cnt;
    const int n = blockIdx.x, tid = threadIdx.x;   // 256 threads
    const float* sp = tops + (size_t)n * PRE;
    if (tid < 64) {
        const int lane = tid;
        const unsigned long long* mb = mask + (size_t)n * PRE * 32;
        // validity: issue all 32 loads independently, then ballot
        float sv[32];
        #pragma unroll
        for (int w = 0; w < 32; ++w) {
            int i = w * 64 + lane;
            sv[w] = (i < PRE) ? sp[i] : -1.0f;
        }
        unsigned long long vbit = 0ull;   // lane w holds validity of rows [64w,64w+64)
        #pragma unroll
        for (int w = 0; w < 32; ++w) {
            unsigned long long m = __ballot(sv[w] > -0.5f);
            if (lane == w) vbit = m;
        }
        unsigned long long remv = 0ull;   // lane l (<32) owns suppression chunk l
        int kc = 0;
        unsigned long long r = mb[(size_t)lane * 32 + 0];  // group-0 rows, chunk 0
        for (int g = 0; g < 32 && kc < POST; ++g) {
            const int base = g * 64;
            const int glen = (PRE - base < 64) ? (PRE - base) : 64;
            unsigned long long cc = rl64(remv, g);
            unsigned long long vb = rl64(vbit, g);
            unsigned long long rr = r;
            if (g + 1 < 32) {   // prefetch next group's row chunks
                int row = (g + 1) * 64 + lane;
                r = (row < PRE) ? mb[(size_t)row * 32 + (g + 1)] : 0ull;
            }
            unsigned long long kb = 0ull;
            for (int jj = 0; jj < glen; ++jj) {
                unsigned long long bit = 1ull << jj;
                if ((vb & bit) && !(cc & bit)) {
                    cc |= rl64(rr, jj);
                    kb |= bit;
                    if (lane == 0) kept[kc] = (unsigned short)(base + jj);
                    ++kc;
                    if (kc == POST) break;
                }
            }
            // fold kept rows into remv: fixed batches of 16 independent loads
            if (kc < POST && kb) {
                unsigned long long kb2 = kb;
                while (kb2) {
                    int idx[16];
                    #pragma unroll
                    for (int t = 0; t < 16; ++t) {
                        if (kb2) {
                            int jj = (int)__builtin_ctzll(kb2);
                            idx[t] = base + jj;
                            kb2 &= kb2 - 1;
                        } else idx[t] = -1;
                    }
                    if (lane < 32) {
                        unsigned long long acc = 0ull;
                        #pragma unroll
                        for (int t = 0; t < 16; ++t) {
                            const unsigned long long* bp =
                                (idx[t] >= 0) ? (mb + (size_t)idx[t] * 32) : dummy;
                            acc |= bp[lane];
                        }
                        remv |= acc;
                    }
                }
            }
        }
        if (lane == 0) cnt = kc;
    }
    __syncthreads();
    const int kc = (cnt < POST) ? cnt : POST;
    for (int rI = tid; rI < POST; rI += 256) {
        float o0 = 0.f, o1 = 0.f, o2 = 0.f, o3 = 0.f, o4 = 0.f;
        if (rI < kc) {
            int i = kept[rI];
            const float* tb = topb + ((size_t)n * PRE + i) * 4;
            o0 = tb[0]; o1 = tb[1]; o2 = tb[2]; o3 = tb[3]; o4 = sp[i];
        }
        float* op = out + ((size_t)n * POST + rI) * 5;
        op[0] = o0; op[1] = o1; op[2] = o2; op[3] = o3; op[4] = o4;
    }
}

extern "C" void kernel_launch(void* const* d_in, const int* in_sizes, int n_in,
                              void* d_out, int out_size, void* d_ws, size_t ws_size,
                              hipStream_t stream) {
    const float* obj    = (const float*)d_in[0];   // [8,15,100,100]
    const float* deltas = (const float*)d_in[1];   // [8,60,100,100]
    float* out = (float*)d_out;                    // [8,1000,5]
    char* ws = (char*)d_ws;

    unsigned*            hist  = (unsigned*)(ws + WS_HIST);
    unsigned*            cnt   = (unsigned*)(ws + WS_CNT);
    unsigned*            bstar = (unsigned*)(ws + WS_BSTAR);
    unsigned long long*  dummy = (unsigned long long*)(ws + WS_DUMMY);
    unsigned long long*  cand  = (unsigned long long*)(ws + WS_CAND);
    float*               topb  = (float*)(ws + WS_TOPB);
    float*               tops  = (float*)(ws + WS_TOPS);
    unsigned long long*  mask  = (unsigned long long*)(ws + WS_MASK);

    hipMemsetAsync(ws, 0, WS_ZEND, stream);
    k_hist       <<<dim3(8, NIMG), 1024, 0, stream>>>(obj, hist);
    k_bstar      <<<NIMG, 64, 0, stream>>>(hist, bstar);
    k_compact    <<<dim3(8, NIMG), 1024, 0, stream>>>(obj, bstar, cand, cnt);
    k_sort_decode<<<NIMG, 1024, 0, stream>>>(cand, deltas, topb, tops);
    k_iou        <<<dim3(63, NIMG), 256, 0, stream>>>(topb, mask);
    k_nms_out    <<<NIMG, 256, 0, stream>>>(topb, tops, mask, dummy, out);
}

// Round 4
// 390.625 us; speedup vs baseline: 2.3820x; 1.2503x over previous
//
#include <hip/hip_runtime.h>
#include <math.h>

// ---------------- problem constants ----------------
#define NIMG   8
#define NA     15
#define GH     100
#define GW     100
#define HW     10000
#define HWA    150000      // NA*HW
#define SLICE  18750       // HWA/8
#define PRE    2000
#define POST   1000
#define CAP    4096        // candidate cap; logit-binning keeps C ~2030
#define NBINS  2048
#define MROWS  2048        // mask rows per image (padded past PRE: staging never OOB)
#define BBOX_CLIP_F 4.135166556742356f
#define IMGSZ  1600.0f
#define BINSCALE 170.6666667f   // NBINS / 12 over logit range [-6,6]

// ---------------- workspace layout (bytes) ----------------
#define WS_HIST   0u            // u32 [8][2048]     65536
#define WS_CNT    65536u        // u32 [8]           32
#define WS_CAND   65600u        // u64 [8][4096]     262144 -> 327744
#define WS_ZEND   327744u       // memset covers hist+cnt+cand
#define WS_TOPB   327744u       // f32 [8][2000][4]  256000 -> 583744
#define WS_TOPS   583744u       // f32 [8][2000]     64000  -> 647744
#define WS_MASK   648192u       // u64 [8][2048][32] 4194304 -> 4842496

// s_waitcnt imm: vmcnt[3:0]+[15:14], expcnt[6:4]=7 (ignore), lgkmcnt[11:8]=15 (ignore)
#define WAIT_VM(n) __builtin_amdgcn_s_waitcnt(((n)&15)|(((n)>>4)<<14)|0xF70)
#define WAIT_LGKM0 __builtin_amdgcn_s_waitcnt(0xC07F)   // lgkmcnt(0), vmcnt=63

// async global->LDS DMA, 16 B/lane, zero VGPR results (compiler can't serialize it)
__device__ __forceinline__ void gl_lds16(const void* g, void* l) {
    __builtin_amdgcn_global_load_lds(
        (const __attribute__((address_space(1))) unsigned int*)g,
        (__attribute__((address_space(3))) unsigned int*)l, 16, 0, 0);
}

// Correctly-rounded f32 exp via double, feeding an IEEE f32 add/div chain.
// Models CPU-reference sigmoid. VERIFIED bit-exact R1/R2/R3.
__device__ __forceinline__ float ref_exp_f32(float x) {
    return (float)exp((double)x);
}
__device__ __forceinline__ float ref_sigmoid(float x) {
    float t = ref_exp_f32(-x);
    return __fdiv_rn(1.0f, __fadd_rn(1.0f, t));
}

// monotone logit->bin map (must be IDENTICAL in k_hist and k_compact)
__device__ __forceinline__ int logit_bin(float x) {
    int b = (int)floorf(__fmul_rn(__fadd_rn(x, 6.0f), BINSCALE));
    return max(0, min(NBINS - 1, b));
}

// 64-bit wave-uniform broadcast via scalar readlane
__device__ __forceinline__ unsigned long long rl64(unsigned long long v, int l) {
    unsigned lo = (unsigned)__builtin_amdgcn_readlane((int)(unsigned)v, l);
    unsigned hi = (unsigned)__builtin_amdgcn_readlane((int)(unsigned)(v >> 32), l);
    return ((unsigned long long)hi << 32) | (unsigned long long)lo;
}

// ---- K1: logit histogram (2048 bins over [-6,6]) ----
// grid (NIMG, 8): linear block id = n + 8*slice -> XCD n (L2 affinity heuristic)
__global__ void k_hist(const float* __restrict__ obj,
                       unsigned* __restrict__ hist) {
    __shared__ unsigned lh[NBINS];
    const int n = blockIdx.x, slice = blockIdx.y, tid = threadIdx.x;
    for (int t = tid; t < NBINS; t += 1024) lh[t] = 0u;
    __syncthreads();
    const float* op = obj + (size_t)n * HWA;
    const int base = slice * SLICE;
    for (int t = tid; t < SLICE; t += 1024) {
        int b = logit_bin(op[base + t]);
        atomicAdd(&lh[b], 1u);
    }
    __syncthreads();
    unsigned* gh = hist + n * NBINS;
    for (int t = tid; t < NBINS; t += 1024)
        if (lh[t]) atomicAdd(&gh[t], lh[t]);
}

// ---- K2: compact candidates (bin >= cutoff b*), b* computed in-block (fused k_bstar)
__global__ void k_compact(const float* __restrict__ obj,
                          const unsigned* __restrict__ hist,
                          unsigned long long* __restrict__ cand,
                          unsigned* __restrict__ cnt) {
    __shared__ int bs_sh;
    const int n = blockIdx.x, slice = blockIdx.y, tid = threadIdx.x;
    if (tid < 64) {   // wave 0: b* = max{b : sum_{x>=b} hist[x] >= PRE}
        const int lane = tid;
        const unsigned* gh = hist + n * NBINS;
        unsigned v[32]; unsigned S = 0;
        #pragma unroll
        for (int t = 0; t < 32; ++t) { v[t] = gh[lane * 32 + t]; S += v[t]; }
        unsigned T = S;
        #pragma unroll
        for (int d = 1; d < 64; d <<= 1) {
            unsigned u = __shfl_down(T, d);
            if (lane + d < 64) T += u;
        }
        unsigned Tn = T - S;
        int bestt = -1; unsigned W = 0;
        #pragma unroll
        for (int t = 31; t >= 0; --t) {
            W += v[t];
            if (bestt < 0 && W + Tn >= PRE) bestt = t;
        }
        unsigned long long hm = __ballot(bestt >= 0);
        int bs = 0;
        if (hm != 0ull) {
            int hl = 63 - __builtin_clzll(hm);
            int bt = __builtin_amdgcn_readlane(bestt, hl);
            bs = hl * 32 + bt;
        }
        if (lane == 0) bs_sh = bs;
    }
    __syncthreads();
    const int bs = bs_sh;
    const float* op = obj + (size_t)n * HWA;
    unsigned long long* cp = cand + (size_t)n * CAP;
    const int base = slice * SLICE;
    for (int t = tid; t < SLICE; t += 1024) {
        int e = base + t;                     // obj layout: e = a*HW + hw
        float x = op[e];
        if (logit_bin(x) >= bs) {
            unsigned sb = __float_as_uint(ref_sigmoid(x));
            unsigned j = (unsigned)((e % HW) * NA + e / HW);  // flat anchor index
            unsigned pos = atomicAdd(&cnt[n], 1u);
            if (pos < CAP)
                cp[pos] = ((unsigned long long)sb << 32) |
                          (unsigned long long)(0xFFFFFFFFu - j);
        }
    }
}

// ---- K3: per-image bitonic sort (2048 if C<=2048, else 4096; desc) + decode ----
__global__ void k_sort_decode(const unsigned long long* __restrict__ cand,
                              const unsigned* __restrict__ cnt,
                              const float* __restrict__ deltas,
                              float* __restrict__ topb,
                              float* __restrict__ tops) {
    __shared__ unsigned long long sk[CAP];
    const int n = blockIdx.x, tid = threadIdx.x;
    const unsigned long long* cp = cand + (size_t)n * CAP;
    const int C = (int)cnt[n];
    const int NEL = (C <= 2048) ? 2048 : CAP;   // slots >= C are zero (memset)
    for (int t = tid; t < NEL; t += 1024) sk[t] = cp[t];
    __syncthreads();
    for (int k = 2; k <= NEL; k <<= 1) {
        for (int j = k >> 1; j > 0; j >>= 1) {
            for (int p = tid; p < (NEL >> 1); p += 1024) {
                int t = ((p & ~(j - 1)) << 1) | (p & (j - 1));
                int ixj = t | j;
                unsigned long long a = sk[t], b = sk[ixj];
                bool up = (t & k) == 0;
                if (up ? (a < b) : (a > b)) { sk[t] = b; sk[ixj] = a; }
            }
            __syncthreads();
        }
    }
    // decode the top PRE entries (C >= PRE guaranteed by cutoff choice)
    const float* dp = deltas + (size_t)n * (NA * 4 * HW);
    for (int t = tid; t < PRE; t += 1024) {
        unsigned long long key = sk[t];
        unsigned sb = (unsigned)(key >> 32);
        unsigned j  = 0xFFFFFFFFu - (unsigned)(key & 0xFFFFFFFFull);
        float s = __uint_as_float(sb);
        int a  = (int)(j % NA), hw = (int)(j / NA);
        int gy = hw / GW, gx = hw % GW;
        int r  = a / 5, si = a % 5;
        // cell anchor, bit-exact vs reference f32 math
        float ratio = (r == 0) ? 0.5f : ((r == 1) ? 1.0f : 2.0f);
        float hr = __fsqrt_rn(ratio);
        float wr = __fdiv_rn(1.0f, hr);
        float scale = (float)(32 << si);
        float wsz = __fmul_rn(wr, scale);
        float hsz = __fmul_rn(hr, scale);
        float bx1 = rintf(__fmul_rn(-wsz, 0.5f));
        float by1 = rintf(__fmul_rn(-hsz, 0.5f));
        float bx2 = rintf(__fmul_rn(wsz, 0.5f));
        float by2 = rintf(__fmul_rn(hsz, 0.5f));
        float sx = (float)(gx * 16), sy = (float)(gy * 16);
        float ax1 = sx + bx1, ay1 = sy + by1, ax2 = sx + bx2, ay2 = sy + by2;
        float wa = __fsub_rn(ax2, ax1), ha = __fsub_rn(ay2, ay1);
        float cxa = __fadd_rn(ax1, __fmul_rn(0.5f, wa));
        float cya = __fadd_rn(ay1, __fmul_rn(0.5f, ha));
        int off = gy * GW + gx;
        float dx = dp[(a * 4 + 0) * HW + off];
        float dy = dp[(a * 4 + 1) * HW + off];
        float dw = fminf(dp[(a * 4 + 2) * HW + off], BBOX_CLIP_F);
        float dh = fminf(dp[(a * 4 + 3) * HW + off], BBOX_CLIP_F);
        float cx = __fadd_rn(__fmul_rn(dx, wa), cxa);
        float cy = __fadd_rn(__fmul_rn(dy, ha), cya);
        float bw = __fmul_rn(ref_exp_f32(dw), wa);
        float bh = __fmul_rn(ref_exp_f32(dh), ha);
        float hbw = __fmul_rn(0.5f, bw), hbh = __fmul_rn(0.5f, bh);
        float x1 = fminf(fmaxf(__fsub_rn(cx, hbw), 0.0f), IMGSZ);
        float y1 = fminf(fmaxf(__fsub_rn(cy, hbh), 0.0f), IMGSZ);
        float x2 = fminf(fmaxf(__fadd_rn(cx, hbw), 0.0f), IMGSZ);
        float y2 = fminf(fmaxf(__fadd_rn(cy, hbh), 0.0f), IMGSZ);
        float* tb = topb + ((size_t)n * PRE + t) * 4;
        tb[0] = x1; tb[1] = y1; tb[2] = x2; tb[3] = y2;
        bool valid = (__fsub_rn(x2, x1) >= 1e-3f) && (__fsub_rn(y2, y1) >= 1e-3f);
        tops[(size_t)n * PRE + t] = valid ? s : -1.0f;
    }
}

// ---- K4: 2000x2000 IoU suppression bitmask (bit j of row i: j>i && iou>0.7) ----
// grid (NIMG, 63): all of image n's blocks land on XCD n -> mask stays in that L2
__global__ void k_iou(const float* __restrict__ topb,
                      unsigned long long* __restrict__ mask) {
    __shared__ float X1[PRE], Y1[PRE], X2[PRE], Y2[PRE];
    const int n = blockIdx.x, rowblk = blockIdx.y, tid = threadIdx.x;
    const float4* tb4 = (const float4*)(topb + (size_t)n * PRE * 4);
    for (int t = tid; t < PRE; t += 256) {
        float4 b = tb4[t];
        X1[t] = b.x; Y1[t] = b.y; X2[t] = b.z; Y2[t] = b.w;
    }
    __syncthreads();
    const int wave = tid >> 6, lane = tid & 63;
    for (int rr = 0; rr < 8; ++rr) {
        int i = rowblk * 32 + wave * 8 + rr;
        if (i >= PRE) break;
        float bi0 = X1[i], bi1 = Y1[i], bi2 = X2[i], bi3 = Y2[i];
        float ai = __fmul_rn(__fsub_rn(bi2, bi0), __fsub_rn(bi3, bi1));
        unsigned long long* mrow = mask + ((size_t)n * MROWS + i) * 32;
        for (int c = 0; c < 32; ++c) {
            int j = c * 64 + lane;
            bool bit = false;
            if (j < PRE && j > i) {
                float bj0 = X1[j], bj1 = Y1[j], bj2 = X2[j], bj3 = Y2[j];
                float aj = __fmul_rn(__fsub_rn(bj2, bj0), __fsub_rn(bj3, bj1));
                float ltx = fmaxf(bi0, bj0), lty = fmaxf(bi1, bj1);
                float rbx = fminf(bi2, bj2), rby = fminf(bi3, bj3);
                float ww = fmaxf(__fsub_rn(rbx, ltx), 0.0f);
                float hh = fmaxf(__fsub_rn(rby, lty), 0.0f);
                float inter = __fmul_rn(ww, hh);
                float denom = __fadd_rn(__fsub_rn(__fadd_rn(ai, aj), inter), 1e-6f);
                bit = __fdiv_rn(inter, denom) > 0.7f;
            }
            unsigned long long m = __ballot(bit);
            if (lane == 0) mrow[c] = m;
        }
    }
}

// ---- K5: greedy NMS. ff1-skip decisions; mask rows staged to LDS via
// global_load_lds DMA two groups ahead (zero-VGPR, can't be serialized by RA).
__global__ void __launch_bounds__(256) k_nms_out(
        const float* __restrict__ topb,
        const float* __restrict__ tops,
        const unsigned long long* __restrict__ mask,
        float* __restrict__ out) {
    __shared__ unsigned long long sbuf[2][2048];   // 2 x 16 KB staging (64 rows each)
    __shared__ float sval[2048];                   // scores (8 KB; 192 B slack in ws)
    __shared__ unsigned short kept[POST];
    __shared__ int cnt;
    const int n = blockIdx.x, tid = threadIdx.x;   // 256 threads; wave 0 does NMS
    const float* sp = tops + (size_t)n * PRE;
    if (tid < 64) {
        const int lane = tid;
        const unsigned long long* mb = mask + (size_t)n * MROWS * 32;
        // stage scores via DMA
        #pragma unroll
        for (int k = 0; k < 8; ++k)
            gl_lds16((const char*)sp + k * 1024 + lane * 16, (char*)sval + k * 1024);
        WAIT_VM(0);
        unsigned long long vbit = 0ull;   // lane w<32: validity of rows [64w,64w+64)
        #pragma unroll
        for (int w = 0; w < 32; ++w) {
            int i = w * 64 + lane;
            bool v = (i < PRE) && (sval[i] > -0.5f);
            unsigned long long m = __ballot(v);
            if (lane == w) vbit = m;
        }
        // prologue: stage(0), r(0), stage(1), r(1)  [stage(k) always before r(k)]
        {
            const char* gb = (const char*)mb;
            #pragma unroll
            for (int k = 0; k < 16; ++k)
                gl_lds16(gb + k * 1024 + lane * 16, (char*)&sbuf[0][0] + k * 1024);
        }
        unsigned long long r = mb[(size_t)lane * 32 + 0];
        {
            const char* gb = (const char*)(mb + (size_t)64 * 32);
            #pragma unroll
            for (int k = 0; k < 16; ++k)
                gl_lds16(gb + k * 1024 + lane * 16, (char*)&sbuf[1][0] + k * 1024);
        }
        unsigned long long rn = mb[(size_t)(64 + lane) * 32 + 1];

        unsigned long long remv = 0ull;   // lane l owns suppression chunk (l&31)
        int kc = 0;
        for (int g = 0; g < 32; ++g) {
            const int base = g * 64;
            unsigned long long cc = rl64(remv, g);
            unsigned long long vb = rl64(vbit, g);
            unsigned long long rr = r;     // row (base+lane) chunk g [compiler waits]
            unsigned long long todo = vb & ~cc;
            unsigned long long kb = 0ull;
            while (todo) {
                int jj = (int)__builtin_ctzll(todo);
                kb |= (1ull << jj);
                if (lane == 0) kept[kc] = (unsigned short)(base + jj);
                ++kc;
                if (kc == POST) break;
                unsigned long long sup = rl64(rr, jj);
                todo &= ~(sup | (1ull << jj));
            }
            if (kc >= POST || g == 31) break;   // no future groups -> no fold needed
            // stage(g) guaranteed done at vmcnt<=18 (younger: r(g), stage(g+1), r(g+1))
            WAIT_VM(18);
            const unsigned long long* sb = sbuf[g & 1];
            int h = lane >> 5, c = lane & 31;
            unsigned kbl = (unsigned)(h ? (kb >> 32) : kb);
            unsigned long long acc = 0ull;
            #pragma unroll
            for (int q = 0; q < 32; ++q) {
                unsigned long long v = sb[(h * 32 + q) * 32 + c];
                acc |= ((kbl >> q) & 1u) ? v : 0ull;
            }
            acc |= __shfl(acc, lane ^ 32);   // merge row-halves
            remv |= acc;
            WAIT_LGKM0;                      // LDS reads done before DMA overwrites
            if (g + 2 < 32) {                // stage(g+2) into same-parity buffer
                const char* gb = (const char*)(mb + (size_t)(g + 2) * 64 * 32);
                char* lb = (char*)&sbuf[g & 1][0];
                #pragma unroll
                for (int k = 0; k < 16; ++k)
                    gl_lds16(gb + k * 1024 + lane * 16, lb + k * 1024);
                r = rn;
                rn = mb[(size_t)((g + 2) * 64 + lane) * 32 + (g + 2)];
            } else {
                r = rn;
            }
        }
        if (lane == 0) cnt = kc;
    }
    __syncthreads();
    const int kc = (cnt < POST) ? cnt : POST;
    for (int rI = tid; rI < POST; rI += 256) {
        float o0 = 0.f, o1 = 0.f, o2 = 0.f, o3 = 0.f, o4 = 0.f;
        if (rI < kc) {
            int i = kept[rI];
            const float* tb = topb + ((size_t)n * PRE + i) * 4;
            o0 = tb[0]; o1 = tb[1]; o2 = tb[2]; o3 = tb[3]; o4 = sval[i];
        }
        float* op = out + ((size_t)n * POST + rI) * 5;
        op[0] = o0; op[1] = o1; op[2] = o2; op[3] = o3; op[4] = o4;
    }
}

extern "C" void kernel_launch(void* const* d_in, const int* in_sizes, int n_in,
                              void* d_out, int out_size, void* d_ws, size_t ws_size,
                              hipStream_t stream) {
    const float* obj    = (const float*)d_in[0];   // [8,15,100,100]
    const float* deltas = (const float*)d_in[1];   // [8,60,100,100]
    float* out = (float*)d_out;                    // [8,1000,5]
    char* ws = (char*)d_ws;

    unsigned*            hist  = (unsigned*)(ws + WS_HIST);
    unsigned*            cnt   = (unsigned*)(ws + WS_CNT);
    unsigned long long*  cand  = (unsigned long long*)(ws + WS_CAND);
    float*               topb  = (float*)(ws + WS_TOPB);
    float*               tops  = (float*)(ws + WS_TOPS);
    unsigned long long*  mask  = (unsigned long long*)(ws + WS_MASK);

    hipMemsetAsync(ws, 0, WS_ZEND, stream);
    k_hist       <<<dim3(NIMG, 8), 1024, 0, stream>>>(obj, hist);
    k_compact    <<<dim3(NIMG, 8), 1024, 0, stream>>>(obj, hist, cand, cnt);
    k_sort_decode<<<NIMG, 1024, 0, stream>>>(cand, cnt, deltas, topb, tops);
    k_iou        <<<dim3(NIMG, 63), 256, 0, stream>>>(topb, mask);
    k_nms_out    <<<NIMG, 256, 0, stream>>>(topb, tops, mask, out);
}

// Round 5
// 272.784 us; speedup vs baseline: 3.4111x; 1.4320x over previous
//
#include <hip/hip_runtime.h>
#include <math.h>

// ---------------- problem constants ----------------
#define NIMG   8
#define NA     15
#define GH     100
#define GW     100
#define HW     10000
#define HWA    150000      // NA*HW
#define SLICE  18750       // HWA/8
#define PRE    2000
#define POST   1000
#define CAP    4096        // candidate cap; logit-binning keeps C ~2030
#define NBINS  2048
#define MROWS  2048        // mask rows per image (padded past PRE: staging never OOB)
#define LBUF   2048        // per-block LDS candidate buffer (mean ~250, 8x slack)
#define BBOX_CLIP_F 4.135166556742356f
#define IMGSZ  1600.0f
#define BINSCALE 170.6666667f   // NBINS / 12 over logit range [-6,6]

// ---------------- workspace layout (bytes) ----------------
#define WS_CNT    0u            // u32 [8]              32
#define WS_CAND   64u           // u64 [8][4096]        262144 -> 262208
#define WS_ZEND   262208u       // memset covers cnt+cand only
#define WS_PHIST  262208u       // u32 [8][8][2048]     524288 -> 786496 (fully written)
#define WS_TOPB   786496u       // f32 [8][2000][4]     256000 -> 1042496
#define WS_TOPS   1042496u      // f32 [8][2000]        64000  -> 1106496
#define WS_MASK   1106496u      // u64 [8][2048][32]    4194304 -> 5300800

// s_waitcnt imm: vmcnt[3:0]+[15:14], expcnt[6:4]=7 (ignore), lgkmcnt[11:8]=15 (ignore)
#define WAIT_VM(n) __builtin_amdgcn_s_waitcnt(((n)&15)|(((n)>>4)<<14)|0xF70)
#define WAIT_LGKM0 __builtin_amdgcn_s_waitcnt(0xC07F)   // lgkmcnt(0), vmcnt=63

// async global->LDS DMA, 16 B/lane, zero VGPR results (compiler can't serialize it)
__device__ __forceinline__ void gl_lds16(const void* g, void* l) {
    __builtin_amdgcn_global_load_lds(
        (const __attribute__((address_space(1))) unsigned int*)g,
        (__attribute__((address_space(3))) unsigned int*)l, 16, 0, 0);
}

// Correctly-rounded f32 exp via double, feeding an IEEE f32 add/div chain.
// Models CPU-reference sigmoid. VERIFIED bit-exact R1-R4.
__device__ __forceinline__ float ref_exp_f32(float x) {
    return (float)exp((double)x);
}
__device__ __forceinline__ float ref_sigmoid(float x) {
    float t = ref_exp_f32(-x);
    return __fdiv_rn(1.0f, __fadd_rn(1.0f, t));
}

// monotone logit->bin map (must be IDENTICAL in k_hist and k_compact)
__device__ __forceinline__ int logit_bin(float x) {
    int b = (int)floorf(__fmul_rn(__fadd_rn(x, 6.0f), BINSCALE));
    return max(0, min(NBINS - 1, b));
}

// 64-bit wave-uniform broadcast via scalar readlane
__device__ __forceinline__ unsigned long long rl64(unsigned long long v, int l) {
    unsigned lo = (unsigned)__builtin_amdgcn_readlane((int)(unsigned)v, l);
    unsigned hi = (unsigned)__builtin_amdgcn_readlane((int)(unsigned)(v >> 32), l);
    return ((unsigned long long)hi << 32) | (unsigned long long)lo;
}

// ---- K1: logit histogram -> per-(image,slice) PARTIAL hist, plain stores ----
// grid (NIMG, 8): linear block id = n + 8*slice -> XCD n (L2 affinity heuristic)
__global__ void k_hist(const float* __restrict__ obj,
                       unsigned* __restrict__ phist) {
    __shared__ unsigned lh[NBINS];
    const int n = blockIdx.x, slice = blockIdx.y, tid = threadIdx.x;
    for (int t = tid; t < NBINS; t += 1024) lh[t] = 0u;
    __syncthreads();
    const float* op = obj + (size_t)n * HWA;
    const int base = slice * SLICE;
    for (int t = tid; t < SLICE; t += 1024) {
        int b = logit_bin(op[base + t]);
        atomicAdd(&lh[b], 1u);
    }
    __syncthreads();
    unsigned* ph = phist + ((size_t)n * 8 + slice) * NBINS;
    for (int t = tid; t < NBINS; t += 1024) ph[t] = lh[t];   // no global atomics
}

// ---- K2: sum partials in LDS, b* in-block, compact via LDS staging ----
// ONE global atomic per block (range reservation) instead of one per candidate.
__global__ void k_compact(const float* __restrict__ obj,
                          const unsigned* __restrict__ phist,
                          unsigned long long* __restrict__ cand,
                          unsigned* __restrict__ cnt) {
    __shared__ unsigned shist[NBINS];              // 8 KB
    __shared__ unsigned long long lbuf[LBUF];      // 16 KB candidate staging
    __shared__ unsigned lcnt_sh, gbase_sh;
    __shared__ int bs_sh;
    const int n = blockIdx.x, slice = blockIdx.y, tid = threadIdx.x;
    // phase 1: all threads sum the 8 partial histograms (independent loads)
    const unsigned* ph = phist + (size_t)n * 8 * NBINS;
    for (int b = tid; b < NBINS; b += 1024) {
        unsigned s = 0;
        #pragma unroll
        for (int k = 0; k < 8; ++k) s += ph[k * NBINS + b];
        shist[b] = s;
    }
    if (tid == 0) lcnt_sh = 0u;
    __syncthreads();
    // phase 2: wave 0 computes b* = max{b : sum_{x>=b} hist[x] >= PRE}
    if (tid < 64) {
        const int lane = tid;
        unsigned v[32]; unsigned S = 0;
        #pragma unroll
        for (int t = 0; t < 32; ++t) { v[t] = shist[lane * 32 + t]; S += v[t]; }
        unsigned T = S;
        #pragma unroll
        for (int d = 1; d < 64; d <<= 1) {
            unsigned u = __shfl_down(T, d);
            if (lane + d < 64) T += u;
        }
        unsigned Tn = T - S;
        int bestt = -1; unsigned W = 0;
        #pragma unroll
        for (int t = 31; t >= 0; --t) {
            W += v[t];
            if (bestt < 0 && W + Tn >= PRE) bestt = t;
        }
        unsigned long long hm = __ballot(bestt >= 0);
        int bs = 0;
        if (hm != 0ull) {
            int hl = 63 - __builtin_clzll(hm);
            int bt = __builtin_amdgcn_readlane(bestt, hl);
            bs = hl * 32 + bt;
        }
        if (lane == 0) bs_sh = bs;
    }
    __syncthreads();
    // phase 3: scan slice, stage candidates in LDS (shared atomics only)
    const int bs = bs_sh;
    const float* op = obj + (size_t)n * HWA;
    unsigned long long* cp = cand + (size_t)n * CAP;
    const int base = slice * SLICE;
    for (int t = tid; t < SLICE; t += 1024) {
        int e = base + t;                     // obj layout: e = a*HW + hw
        float x = op[e];
        if (logit_bin(x) >= bs) {
            unsigned sb = __float_as_uint(ref_sigmoid(x));
            unsigned j = (unsigned)((e % HW) * NA + e / HW);  // flat anchor index
            unsigned long long key = ((unsigned long long)sb << 32) |
                                     (unsigned long long)(0xFFFFFFFFu - j);
            unsigned p = atomicAdd(&lcnt_sh, 1u);
            if (p < LBUF) lbuf[p] = key;
            else {                            // overflow fallback (not expected)
                unsigned pos = atomicAdd(&cnt[n], 1u);
                if (pos < CAP) cp[pos] = key;
            }
        }
    }
    __syncthreads();
    // phase 4: one global reservation, coalesced flush
    const unsigned L = (lcnt_sh < LBUF) ? lcnt_sh : LBUF;
    if (tid == 0) gbase_sh = atomicAdd(&cnt[n], L);
    __syncthreads();
    const unsigned gb = gbase_sh;
    for (unsigned t = tid; t < L; t += 1024) {
        unsigned pos = gb + t;
        if (pos < CAP) cp[pos] = lbuf[t];
    }
}

// ---- K3: per-image bitonic sort (2048 if C<=2048, else 4096; desc) + decode ----
__global__ void k_sort_decode(const unsigned long long* __restrict__ cand,
                              const unsigned* __restrict__ cnt,
                              const float* __restrict__ deltas,
                              float* __restrict__ topb,
                              float* __restrict__ tops) {
    __shared__ unsigned long long sk[CAP];
    const int n = blockIdx.x, tid = threadIdx.x;
    const unsigned long long* cp = cand + (size_t)n * CAP;
    const int C = (int)cnt[n];
    const int NEL = (C <= 2048) ? 2048 : CAP;   // slots >= C are zero (memset)
    for (int t = tid; t < NEL; t += 1024) sk[t] = cp[t];
    __syncthreads();
    for (int k = 2; k <= NEL; k <<= 1) {
        for (int j = k >> 1; j > 0; j >>= 1) {
            for (int p = tid; p < (NEL >> 1); p += 1024) {
                int t = ((p & ~(j - 1)) << 1) | (p & (j - 1));
                int ixj = t | j;
                unsigned long long a = sk[t], b = sk[ixj];
                bool up = (t & k) == 0;
                if (up ? (a < b) : (a > b)) { sk[t] = b; sk[ixj] = a; }
            }
            __syncthreads();
        }
    }
    // decode the top PRE entries (C >= PRE guaranteed by cutoff choice)
    const float* dp = deltas + (size_t)n * (NA * 4 * HW);
    for (int t = tid; t < PRE; t += 1024) {
        unsigned long long key = sk[t];
        unsigned sb = (unsigned)(key >> 32);
        unsigned j  = 0xFFFFFFFFu - (unsigned)(key & 0xFFFFFFFFull);
        float s = __uint_as_float(sb);
        int a  = (int)(j % NA), hw = (int)(j / NA);
        int gy = hw / GW, gx = hw % GW;
        int r  = a / 5, si = a % 5;
        // cell anchor, bit-exact vs reference f32 math
        float ratio = (r == 0) ? 0.5f : ((r == 1) ? 1.0f : 2.0f);
        float hr = __fsqrt_rn(ratio);
        float wr = __fdiv_rn(1.0f, hr);
        float scale = (float)(32 << si);
        float wsz = __fmul_rn(wr, scale);
        float hsz = __fmul_rn(hr, scale);
        float bx1 = rintf(__fmul_rn(-wsz, 0.5f));
        float by1 = rintf(__fmul_rn(-hsz, 0.5f));
        float bx2 = rintf(__fmul_rn(wsz, 0.5f));
        float by2 = rintf(__fmul_rn(hsz, 0.5f));
        float sx = (float)(gx * 16), sy = (float)(gy * 16);
        float ax1 = sx + bx1, ay1 = sy + by1, ax2 = sx + bx2, ay2 = sy + by2;
        float wa = __fsub_rn(ax2, ax1), ha = __fsub_rn(ay2, ay1);
        float cxa = __fadd_rn(ax1, __fmul_rn(0.5f, wa));
        float cya = __fadd_rn(ay1, __fmul_rn(0.5f, ha));
        int off = gy * GW + gx;
        float dx = dp[(a * 4 + 0) * HW + off];
        float dy = dp[(a * 4 + 1) * HW + off];
        float dw = fminf(dp[(a * 4 + 2) * HW + off], BBOX_CLIP_F);
        float dh = fminf(dp[(a * 4 + 3) * HW + off], BBOX_CLIP_F);
        float cx = __fadd_rn(__fmul_rn(dx, wa), cxa);
        float cy = __fadd_rn(__fmul_rn(dy, ha), cya);
        float bw = __fmul_rn(ref_exp_f32(dw), wa);
        float bh = __fmul_rn(ref_exp_f32(dh), ha);
        float hbw = __fmul_rn(0.5f, bw), hbh = __fmul_rn(0.5f, bh);
        float x1 = fminf(fmaxf(__fsub_rn(cx, hbw), 0.0f), IMGSZ);
        float y1 = fminf(fmaxf(__fsub_rn(cy, hbh), 0.0f), IMGSZ);
        float x2 = fminf(fmaxf(__fadd_rn(cx, hbw), 0.0f), IMGSZ);
        float y2 = fminf(fmaxf(__fadd_rn(cy, hbh), 0.0f), IMGSZ);
        float* tb = topb + ((size_t)n * PRE + t) * 4;
        tb[0] = x1; tb[1] = y1; tb[2] = x2; tb[3] = y2;
        bool valid = (__fsub_rn(x2, x1) >= 1e-3f) && (__fsub_rn(y2, y1) >= 1e-3f);
        tops[(size_t)n * PRE + t] = valid ? s : -1.0f;
    }
}

// ---- K4: 2000x2000 IoU suppression bitmask (bit j of row i: j>i && iou>0.7) ----
// grid (NIMG, 63): all of image n's blocks land on XCD n -> mask stays in that L2
__global__ void k_iou(const float* __restrict__ topb,
                      unsigned long long* __restrict__ mask) {
    __shared__ float X1[PRE], Y1[PRE], X2[PRE], Y2[PRE];
    const int n = blockIdx.x, rowblk = blockIdx.y, tid = threadIdx.x;
    const float4* tb4 = (const float4*)(topb + (size_t)n * PRE * 4);
    for (int t = tid; t < PRE; t += 256) {
        float4 b = tb4[t];
        X1[t] = b.x; Y1[t] = b.y; X2[t] = b.z; Y2[t] = b.w;
    }
    __syncthreads();
    const int wave = tid >> 6, lane = tid & 63;
    for (int rr = 0; rr < 8; ++rr) {
        int i = rowblk * 32 + wave * 8 + rr;
        if (i >= PRE) break;
        float bi0 = X1[i], bi1 = Y1[i], bi2 = X2[i], bi3 = Y2[i];
        float ai = __fmul_rn(__fsub_rn(bi2, bi0), __fsub_rn(bi3, bi1));
        unsigned long long* mrow = mask + ((size_t)n * MROWS + i) * 32;
        for (int c = 0; c < 32; ++c) {
            int j = c * 64 + lane;
            bool bit = false;
            if (j < PRE && j > i) {
                float bj0 = X1[j], bj1 = Y1[j], bj2 = X2[j], bj3 = Y2[j];
                float aj = __fmul_rn(__fsub_rn(bj2, bj0), __fsub_rn(bj3, bj1));
                float ltx = fmaxf(bi0, bj0), lty = fmaxf(bi1, bj1);
                float rbx = fminf(bi2, bj2), rby = fminf(bi3, bj3);
                float ww = fmaxf(__fsub_rn(rbx, ltx), 0.0f);
                float hh = fmaxf(__fsub_rn(rby, lty), 0.0f);
                float inter = __fmul_rn(ww, hh);
                float denom = __fadd_rn(__fsub_rn(__fadd_rn(ai, aj), inter), 1e-6f);
                bit = __fdiv_rn(inter, denom) > 0.7f;
            }
            unsigned long long m = __ballot(bit);
            if (lane == 0) mrow[c] = m;
        }
    }
}

// ---- K5: greedy NMS. ff1-skip decisions; mask rows staged to LDS via
// global_load_lds DMA two groups ahead (zero-VGPR, can't be serialized by RA).
__global__ void __launch_bounds__(256) k_nms_out(
        const float* __restrict__ topb,
        const float* __restrict__ tops,
        const unsigned long long* __restrict__ mask,
        float* __restrict__ out) {
    __shared__ unsigned long long sbuf[2][2048];   // 2 x 16 KB staging (64 rows each)
    __shared__ float sval[2048];                   // scores (8 KB)
    __shared__ unsigned short kept[POST];
    __shared__ int cnt;
    const int n = blockIdx.x, tid = threadIdx.x;   // 256 threads; wave 0 does NMS
    const float* sp = tops + (size_t)n * PRE;
    if (tid < 64) {
        const int lane = tid;
        const unsigned long long* mb = mask + (size_t)n * MROWS * 32;
        // stage scores via DMA
        #pragma unroll
        for (int k = 0; k < 8; ++k)
            gl_lds16((const char*)sp + k * 1024 + lane * 16, (char*)sval + k * 1024);
        WAIT_VM(0);
        unsigned long long vbit = 0ull;   // lane w<32: validity of rows [64w,64w+64)
        #pragma unroll
        for (int w = 0; w < 32; ++w) {
            int i = w * 64 + lane;
            bool v = (i < PRE) && (sval[i] > -0.5f);
            unsigned long long m = __ballot(v);
            if (lane == w) vbit = m;
        }
        // prologue: stage(0), r(0), stage(1), r(1)  [stage(k) always before r(k)]
        {
            const char* gb = (const char*)mb;
            #pragma unroll
            for (int k = 0; k < 16; ++k)
                gl_lds16(gb + k * 1024 + lane * 16, (char*)&sbuf[0][0] + k * 1024);
        }
        unsigned long long r = mb[(size_t)lane * 32 + 0];
        {
            const char* gb = (const char*)(mb + (size_t)64 * 32);
            #pragma unroll
            for (int k = 0; k < 16; ++k)
                gl_lds16(gb + k * 1024 + lane * 16, (char*)&sbuf[1][0] + k * 1024);
        }
        unsigned long long rn = mb[(size_t)(64 + lane) * 32 + 1];

        unsigned long long remv = 0ull;   // lane l owns suppression chunk (l&31)
        int kc = 0;
        for (int g = 0; g < 32; ++g) {
            const int base = g * 64;
            unsigned long long cc = rl64(remv, g);
            unsigned long long vb = rl64(vbit, g);
            unsigned long long rr = r;     // row (base+lane) chunk g [compiler waits]
            unsigned long long todo = vb & ~cc;
            unsigned long long kb = 0ull;
            while (todo) {
                int jj = (int)__builtin_ctzll(todo);
                kb |= (1ull << jj);
                if (lane == 0) kept[kc] = (unsigned short)(base + jj);
                ++kc;
                if (kc == POST) break;
                unsigned long long sup = rl64(rr, jj);
                todo &= ~(sup | (1ull << jj));
            }
            if (kc >= POST || g == 31) break;   // no future groups -> no fold needed
            // stage(g) guaranteed done at vmcnt<=18 (younger: r(g), stage(g+1), r(g+1))
            WAIT_VM(18);
            const unsigned long long* sb = sbuf[g & 1];
            int h = lane >> 5, c = lane & 31;
            unsigned kbl = (unsigned)(h ? (kb >> 32) : kb);
            unsigned long long acc = 0ull;
            #pragma unroll
            for (int q = 0; q < 32; ++q) {
                unsigned long long v = sb[(h * 32 + q) * 32 + c];
                acc |= ((kbl >> q) & 1u) ? v : 0ull;
            }
            acc |= __shfl(acc, lane ^ 32);   // merge row-halves
            remv |= acc;
            WAIT_LGKM0;                      // LDS reads done before DMA overwrites
            if (g + 2 < 32) {                // stage(g+2) into same-parity buffer
                const char* gb = (const char*)(mb + (size_t)(g + 2) * 64 * 32);
                char* lb = (char*)&sbuf[g & 1][0];
                #pragma unroll
                for (int k = 0; k < 16; ++k)
                    gl_lds16(gb + k * 1024 + lane * 16, lb + k * 1024);
                r = rn;
                rn = mb[(size_t)((g + 2) * 64 + lane) * 32 + (g + 2)];
            } else {
                r = rn;
            }
        }
        if (lane == 0) cnt = kc;
    }
    __syncthreads();
    const int kc = (cnt < POST) ? cnt : POST;
    for (int rI = tid; rI < POST; rI += 256) {
        float o0 = 0.f, o1 = 0.f, o2 = 0.f, o3 = 0.f, o4 = 0.f;
        if (rI < kc) {
            int i = kept[rI];
            const float* tb = topb + ((size_t)n * PRE + i) * 4;
            o0 = tb[0]; o1 = tb[1]; o2 = tb[2]; o3 = tb[3]; o4 = sval[i];
        }
        float* op = out + ((size_t)n * POST + rI) * 5;
        op[0] = o0; op[1] = o1; op[2] = o2; op[3] = o3; op[4] = o4;
    }
}

extern "C" void kernel_launch(void* const* d_in, const int* in_sizes, int n_in,
                              void* d_out, int out_size, void* d_ws, size_t ws_size,
                              hipStream_t stream) {
    const float* obj    = (const float*)d_in[0];   // [8,15,100,100]
    const float* deltas = (const float*)d_in[1];   // [8,60,100,100]
    float* out = (float*)d_out;                    // [8,1000,5]
    char* ws = (char*)d_ws;

    unsigned*            cnt   = (unsigned*)(ws + WS_CNT);
    unsigned long long*  cand  = (unsigned long long*)(ws + WS_CAND);
    unsigned*            phist = (unsigned*)(ws + WS_PHIST);
    float*               topb  = (float*)(ws + WS_TOPB);
    float*               tops  = (float*)(ws + WS_TOPS);
    unsigned long long*  mask  = (unsigned long long*)(ws + WS_MASK);

    hipMemsetAsync(ws, 0, WS_ZEND, stream);
    k_hist       <<<dim3(NIMG, 8), 1024, 0, stream>>>(obj, phist);
    k_compact    <<<dim3(NIMG, 8), 1024, 0, stream>>>(obj, phist, cand, cnt);
    k_sort_decode<<<NIMG, 1024, 0, stream>>>(cand, cnt, deltas, topb, tops);
    k_iou        <<<dim3(NIMG, 63), 256, 0, stream>>>(topb, mask);
    k_nms_out    <<<NIMG, 256, 0, stream>>>(topb, tops, mask, out);
}

// Round 6
// 228.204 us; speedup vs baseline: 4.0774x; 1.1954x over previous
//
#include <hip/hip_runtime.h>
#include <math.h>

// ---------------- problem constants ----------------
#define NIMG   8
#define NA     15
#define GH     100
#define GW     100
#define HW     10000
#define HWA    150000      // NA*HW
#define SLICE  18750       // HWA/8
#define PRE    2000
#define POST   1000
#define CAP    4096        // candidate cap; logit-binning keeps C ~2030
#define NBINS  2048
#define MROWS  2048        // mask rows per image (padded past PRE: staging never OOB)
#define LBUF   2048        // per-block LDS candidate buffer (mean ~250, 8x slack)
#define BBOX_CLIP_F 4.135166556742356f
#define IMGSZ  1600.0f
#define BINSCALE 170.6666667f   // NBINS / 12 over logit range [-6,6]

// ---------------- workspace layout (bytes) ----------------
#define WS_CNT    0u            // u32 [8]              32   (zeroed by k_hist)
#define WS_CAND   64u           // u64 [8][4096]        262144 -> 262208
#define WS_PHIST  262208u       // u32 [8][8][2048]     524288 -> 786496 (fully written)
#define WS_TOPB   786496u       // f32 [8][2000][4]     256000 -> 1042496
#define WS_TOPS   1042496u      // f32 [8][2000]        64000  -> 1106496
#define WS_MASK   1106496u      // u64 [8][2048][32]    4194304 -> 5300800

// s_waitcnt imm: vmcnt[3:0]+[15:14], expcnt[6:4]=7 (ignore), lgkmcnt[11:8]=15 (ignore)
#define WAIT_VM(n) __builtin_amdgcn_s_waitcnt(((n)&15)|(((n)>>4)<<14)|0xF70)
#define WAIT_LGKM0 __builtin_amdgcn_s_waitcnt(0xC07F)   // lgkmcnt(0), vmcnt=63

// async global->LDS DMA, 16 B/lane, zero VGPR results (compiler can't serialize it)
__device__ __forceinline__ void gl_lds16(const void* g, void* l) {
    __builtin_amdgcn_global_load_lds(
        (const __attribute__((address_space(1))) unsigned int*)g,
        (__attribute__((address_space(3))) unsigned int*)l, 16, 0, 0);
}

// Correctly-rounded f32 exp via double, feeding an IEEE f32 add/div chain.
// Models CPU-reference sigmoid. VERIFIED bit-exact R1-R5.
__device__ __forceinline__ float ref_exp_f32(float x) {
    return (float)exp((double)x);
}
__device__ __forceinline__ float ref_sigmoid(float x) {
    float t = ref_exp_f32(-x);
    return __fdiv_rn(1.0f, __fadd_rn(1.0f, t));
}

// monotone logit->bin map (must be IDENTICAL in k_hist and k_compact)
__device__ __forceinline__ int logit_bin(float x) {
    int b = (int)floorf(__fmul_rn(__fadd_rn(x, 6.0f), BINSCALE));
    return max(0, min(NBINS - 1, b));
}

// 64-bit wave-uniform broadcast via scalar readlane
__device__ __forceinline__ unsigned long long rl64(unsigned long long v, int l) {
    unsigned lo = (unsigned)__builtin_amdgcn_readlane((int)(unsigned)v, l);
    unsigned hi = (unsigned)__builtin_amdgcn_readlane((int)(unsigned)(v >> 32), l);
    return ((unsigned long long)hi << 32) | (unsigned long long)lo;
}

// ---- K1: logit histogram -> per-(image,slice) PARTIAL hist, plain stores ----
// grid (NIMG, 8): linear block id = n + 8*slice -> XCD n (L2 affinity heuristic)
__global__ void k_hist(const float* __restrict__ obj,
                       unsigned* __restrict__ phist,
                       unsigned* __restrict__ cnt) {
    __shared__ unsigned lh[NBINS];
    const int n = blockIdx.x, slice = blockIdx.y, tid = threadIdx.x;
    if (slice == 0 && tid == 0) cnt[n] = 0u;   // replaces the memset launch
    for (int t = tid; t < NBINS; t += 1024) lh[t] = 0u;
    __syncthreads();
    const float* op = obj + (size_t)n * HWA;
    const int base = slice * SLICE;
    for (int t = tid; t < SLICE; t += 1024) {
        int b = logit_bin(op[base + t]);
        atomicAdd(&lh[b], 1u);
    }
    __syncthreads();
    unsigned* ph = phist + ((size_t)n * 8 + slice) * NBINS;
    for (int t = tid; t < NBINS; t += 1024) ph[t] = lh[t];   // no global atomics
}

// ---- K2: sum partials in LDS, b* in-block, compact via LDS staging ----
// ONE global atomic per block (range reservation) instead of one per candidate.
__global__ void k_compact(const float* __restrict__ obj,
                          const unsigned* __restrict__ phist,
                          unsigned long long* __restrict__ cand,
                          unsigned* __restrict__ cnt) {
    __shared__ unsigned shist[NBINS];              // 8 KB
    __shared__ unsigned long long lbuf[LBUF];      // 16 KB candidate staging
    __shared__ unsigned lcnt_sh, gbase_sh;
    __shared__ int bs_sh;
    const int n = blockIdx.x, slice = blockIdx.y, tid = threadIdx.x;
    // phase 1: all threads sum the 8 partial histograms (independent loads)
    const unsigned* ph = phist + (size_t)n * 8 * NBINS;
    for (int b = tid; b < NBINS; b += 1024) {
        unsigned s = 0;
        #pragma unroll
        for (int k = 0; k < 8; ++k) s += ph[k * NBINS + b];
        shist[b] = s;
    }
    if (tid == 0) lcnt_sh = 0u;
    __syncthreads();
    // phase 2: wave 0 computes b* = max{b : sum_{x>=b} hist[x] >= PRE}
    if (tid < 64) {
        const int lane = tid;
        unsigned v[32]; unsigned S = 0;
        #pragma unroll
        for (int t = 0; t < 32; ++t) { v[t] = shist[lane * 32 + t]; S += v[t]; }
        unsigned T = S;
        #pragma unroll
        for (int d = 1; d < 64; d <<= 1) {
            unsigned u = __shfl_down(T, d);
            if (lane + d < 64) T += u;
        }
        unsigned Tn = T - S;
        int bestt = -1; unsigned W = 0;
        #pragma unroll
        for (int t = 31; t >= 0; --t) {
            W += v[t];
            if (bestt < 0 && W + Tn >= PRE) bestt = t;
        }
        unsigned long long hm = __ballot(bestt >= 0);
        int bs = 0;
        if (hm != 0ull) {
            int hl = 63 - __builtin_clzll(hm);
            int bt = __builtin_amdgcn_readlane(bestt, hl);
            bs = hl * 32 + bt;
        }
        if (lane == 0) bs_sh = bs;
    }
    __syncthreads();
    // phase 3: scan slice, stage candidates in LDS (shared atomics only)
    const int bs = bs_sh;
    const float* op = obj + (size_t)n * HWA;
    unsigned long long* cp = cand + (size_t)n * CAP;
    const int base = slice * SLICE;
    for (int t = tid; t < SLICE; t += 1024) {
        int e = base + t;                     // obj layout: e = a*HW + hw
        float x = op[e];
        if (logit_bin(x) >= bs) {
            unsigned sb = __float_as_uint(ref_sigmoid(x));
            unsigned j = (unsigned)((e % HW) * NA + e / HW);  // flat anchor index
            unsigned long long key = ((unsigned long long)sb << 32) |
                                     (unsigned long long)(0xFFFFFFFFu - j);
            unsigned p = atomicAdd(&lcnt_sh, 1u);
            if (p < LBUF) lbuf[p] = key;
            else {                            // overflow fallback (not expected)
                unsigned pos = atomicAdd(&cnt[n], 1u);
                if (pos < CAP) cp[pos] = key;
            }
        }
    }
    __syncthreads();
    // phase 4: one global reservation, coalesced flush
    const unsigned L = (lcnt_sh < LBUF) ? lcnt_sh : LBUF;
    if (tid == 0) gbase_sh = atomicAdd(&cnt[n], L);
    __syncthreads();
    const unsigned gb = gbase_sh;
    for (unsigned t = tid; t < L; t += 1024) {
        unsigned pos = gb + t;
        if (pos < CAP) cp[pos] = lbuf[t];
    }
}

// ---- K3: per-image bitonic sort (2048 if C<=2048, else 4096; desc) + decode ----
__global__ void k_sort_decode(const unsigned long long* __restrict__ cand,
                              const unsigned* __restrict__ cnt,
                              const float* __restrict__ deltas,
                              float* __restrict__ topb,
                              float* __restrict__ tops) {
    __shared__ unsigned long long sk[CAP];
    const int n = blockIdx.x, tid = threadIdx.x;
    const unsigned long long* cp = cand + (size_t)n * CAP;
    const int C = (int)cnt[n];
    const int NEL = (C <= 2048) ? 2048 : CAP;
    for (int t = tid; t < NEL; t += 1024)
        sk[t] = (t < C) ? cp[t] : 0ull;        // zero-fill pad (no memset needed)
    __syncthreads();
    for (int k = 2; k <= NEL; k <<= 1) {
        for (int j = k >> 1; j > 0; j >>= 1) {
            for (int p = tid; p < (NEL >> 1); p += 1024) {
                int t = ((p & ~(j - 1)) << 1) | (p & (j - 1));
                int ixj = t | j;
                unsigned long long a = sk[t], b = sk[ixj];
                bool up = (t & k) == 0;
                if (up ? (a < b) : (a > b)) { sk[t] = b; sk[ixj] = a; }
            }
            __syncthreads();
        }
    }
    // decode the top PRE entries (C >= PRE guaranteed by cutoff choice)
    const float* dp = deltas + (size_t)n * (NA * 4 * HW);
    for (int t = tid; t < PRE; t += 1024) {
        unsigned long long key = sk[t];
        unsigned sb = (unsigned)(key >> 32);
        unsigned j  = 0xFFFFFFFFu - (unsigned)(key & 0xFFFFFFFFull);
        float s = __uint_as_float(sb);
        int a  = (int)(j % NA), hw = (int)(j / NA);
        int gy = hw / GW, gx = hw % GW;
        int r  = a / 5, si = a % 5;
        // cell anchor, bit-exact vs reference f32 math
        float ratio = (r == 0) ? 0.5f : ((r == 1) ? 1.0f : 2.0f);
        float hr = __fsqrt_rn(ratio);
        float wr = __fdiv_rn(1.0f, hr);
        float scale = (float)(32 << si);
        float wsz = __fmul_rn(wr, scale);
        float hsz = __fmul_rn(hr, scale);
        float bx1 = rintf(__fmul_rn(-wsz, 0.5f));
        float by1 = rintf(__fmul_rn(-hsz, 0.5f));
        float bx2 = rintf(__fmul_rn(wsz, 0.5f));
        float by2 = rintf(__fmul_rn(hsz, 0.5f));
        float sx = (float)(gx * 16), sy = (float)(gy * 16);
        float ax1 = sx + bx1, ay1 = sy + by1, ax2 = sx + bx2, ay2 = sy + by2;
        float wa = __fsub_rn(ax2, ax1), ha = __fsub_rn(ay2, ay1);
        float cxa = __fadd_rn(ax1, __fmul_rn(0.5f, wa));
        float cya = __fadd_rn(ay1, __fmul_rn(0.5f, ha));
        int off = gy * GW + gx;
        float dx = dp[(a * 4 + 0) * HW + off];
        float dy = dp[(a * 4 + 1) * HW + off];
        float dw = fminf(dp[(a * 4 + 2) * HW + off], BBOX_CLIP_F);
        float dh = fminf(dp[(a * 4 + 3) * HW + off], BBOX_CLIP_F);
        float cx = __fadd_rn(__fmul_rn(dx, wa), cxa);
        float cy = __fadd_rn(__fmul_rn(dy, ha), cya);
        float bw = __fmul_rn(ref_exp_f32(dw), wa);
        float bh = __fmul_rn(ref_exp_f32(dh), ha);
        float hbw = __fmul_rn(0.5f, bw), hbh = __fmul_rn(0.5f, bh);
        float x1 = fminf(fmaxf(__fsub_rn(cx, hbw), 0.0f), IMGSZ);
        float y1 = fminf(fmaxf(__fsub_rn(cy, hbh), 0.0f), IMGSZ);
        float x2 = fminf(fmaxf(__fadd_rn(cx, hbw), 0.0f), IMGSZ);
        float y2 = fminf(fmaxf(__fadd_rn(cy, hbh), 0.0f), IMGSZ);
        float* tb = topb + ((size_t)n * PRE + t) * 4;
        tb[0] = x1; tb[1] = y1; tb[2] = x2; tb[3] = y2;
        bool valid = (__fsub_rn(x2, x1) >= 1e-3f) && (__fsub_rn(y2, y1) >= 1e-3f);
        tops[(size_t)n * PRE + t] = valid ? s : -1.0f;
    }
}

// ---- K4: 2000x2000 IoU suppression bitmask (bit j of row i: j>i && iou>0.7) ----
// grid (NIMG, 63): all of image n's blocks land on XCD n -> mask stays in that L2
__global__ void k_iou(const float* __restrict__ topb,
                      unsigned long long* __restrict__ mask) {
    __shared__ float X1[PRE], Y1[PRE], X2[PRE], Y2[PRE];
    const int n = blockIdx.x, rowblk = blockIdx.y, tid = threadIdx.x;
    const float4* tb4 = (const float4*)(topb + (size_t)n * PRE * 4);
    for (int t = tid; t < PRE; t += 256) {
        float4 b = tb4[t];
        X1[t] = b.x; Y1[t] = b.y; X2[t] = b.z; Y2[t] = b.w;
    }
    __syncthreads();
    const int wave = tid >> 6, lane = tid & 63;
    for (int rr = 0; rr < 8; ++rr) {
        int i = rowblk * 32 + wave * 8 + rr;
        if (i >= PRE) break;
        float bi0 = X1[i], bi1 = Y1[i], bi2 = X2[i], bi3 = Y2[i];
        float ai = __fmul_rn(__fsub_rn(bi2, bi0), __fsub_rn(bi3, bi1));
        unsigned long long* mrow = mask + ((size_t)n * MROWS + i) * 32;
        unsigned long long mval = 0ull;     // lane c<32 collects chunk c
        for (int c = 0; c < 32; ++c) {
            int j = c * 64 + lane;
            bool bit = false;
            if (j < PRE && j > i) {
                float bj0 = X1[j], bj1 = Y1[j], bj2 = X2[j], bj3 = Y2[j];
                float aj = __fmul_rn(__fsub_rn(bj2, bj0), __fsub_rn(bj3, bj1));
                float ltx = fmaxf(bi0, bj0), lty = fmaxf(bi1, bj1);
                float rbx = fminf(bi2, bj2), rby = fminf(bi3, bj3);
                float ww = fmaxf(__fsub_rn(rbx, ltx), 0.0f);
                float hh = fmaxf(__fsub_rn(rby, lty), 0.0f);
                float inter = __fmul_rn(ww, hh);
                float denom = __fadd_rn(__fsub_rn(__fadd_rn(ai, aj), inter), 1e-6f);
                bit = __fdiv_rn(inter, denom) > 0.7f;
            }
            unsigned long long m = __ballot(bit);
            if (lane == c) mval = m;
        }
        if (lane < 32) mrow[lane] = mval;   // one coalesced 256B store per row
    }
}

// ---- K5: greedy NMS. Pure-scalar decision chain; rr from the staged LDS buffer
// (no per-group global loads); parallel kept-emission; DMA two groups ahead.
__global__ void __launch_bounds__(256) k_nms_out(
        const float* __restrict__ topb,
        const float* __restrict__ tops,
        const unsigned long long* __restrict__ mask,
        float* __restrict__ out) {
    __shared__ unsigned long long sbuf[2][2048];   // 2 x 16 KB staging (64 rows each)
    __shared__ float sval[2048];                   // scores (8 KB)
    __shared__ unsigned short kept[POST];
    __shared__ int cnt;
    const int n = blockIdx.x, tid = threadIdx.x;   // 256 threads; wave 0 does NMS
    const float* sp = tops + (size_t)n * PRE;
    if (tid < 64) {
        const int lane = tid;
        const unsigned long long* mb = mask + (size_t)n * MROWS * 32;
        // stage scores via DMA
        #pragma unroll
        for (int k = 0; k < 8; ++k)
            gl_lds16((const char*)sp + k * 1024 + lane * 16, (char*)sval + k * 1024);
        WAIT_VM(0);
        unsigned long long vbit = 0ull;   // lane w<32: validity of rows [64w,64w+64)
        #pragma unroll
        for (int w = 0; w < 32; ++w) {
            int i = w * 64 + lane;
            bool v = (i < PRE) && (sval[i] > -0.5f);
            unsigned long long m = __ballot(v);
            if (lane == w) vbit = m;
        }
        // prologue: stage groups 0 and 1
        #pragma unroll
        for (int k = 0; k < 16; ++k)
            gl_lds16((const char*)mb + k * 1024 + lane * 16,
                     (char*)&sbuf[0][0] + k * 1024);
        #pragma unroll
        for (int k = 0; k < 16; ++k)
            gl_lds16((const char*)(mb + (size_t)64 * 32) + k * 1024 + lane * 16,
                     (char*)&sbuf[1][0] + k * 1024);

        unsigned long long remv = 0ull;   // lane l owns suppression chunk (l&31)
        int kc = 0;
        for (int g = 0; g < 32; ++g) {
            const int base = g * 64;
            WAIT_VM(16);                   // stage(g) done; stage(g+1) may fly
            const unsigned long long* sb = sbuf[g & 1];
            // row (base+lane)'s chunk g (bank-aliased read, once per group)
            unsigned long long rr = sb[(size_t)lane * 32 + g];
            unsigned long long cc = rl64(remv, g);
            unsigned long long vb = rl64(vbit, g);
            // pure scalar greedy chain (no POST check: surplus kept are harmless,
            // reference also computes full keep then takes first POST)
            unsigned long long todo = vb & ~cc;
            unsigned long long kb = 0ull;
            while (todo) {
                int jj = (int)__builtin_ctzll(todo);
                unsigned long long bit = 1ull << jj;
                kb |= bit;
                unsigned long long sup = rl64(rr, jj);
                todo &= ~(sup | bit);
            }
            // parallel emission: rank by popcount-below
            if (kb) {
                if ((kb >> lane) & 1ull) {
                    int rank = __popcll(kb & ((1ull << lane) - 1ull));
                    int pos = kc + rank;
                    if (pos < POST) kept[pos] = (unsigned short)(base + lane);
                }
                kc += __popcll(kb);
            }
            if (kc >= POST || g == 31) break;   // future groups irrelevant
            // fold kept rows' full masks into remv (off the decision chain)
            if (kb) {
                int h = lane >> 5, c = lane & 31;
                unsigned kbl = (unsigned)(h ? (kb >> 32) : kb);
                unsigned long long acc = 0ull;
                #pragma unroll
                for (int q = 0; q < 32; ++q) {
                    unsigned long long v = sb[(h * 32 + q) * 32 + c];
                    acc |= ((kbl >> q) & 1u) ? v : 0ull;
                }
                acc |= __shfl(acc, lane ^ 32);   // merge row-halves
                remv |= acc;
            }
            WAIT_LGKM0;                      // LDS reads done before DMA overwrites
            if (g + 2 < 32) {                // stage(g+2) into same-parity buffer
                const char* gb = (const char*)(mb + (size_t)(g + 2) * 64 * 32);
                char* lb = (char*)&sbuf[g & 1][0];
                #pragma unroll
                for (int k = 0; k < 16; ++k)
                    gl_lds16(gb + k * 1024 + lane * 16, lb + k * 1024);
            }
        }
        if (lane == 0) cnt = (kc < POST) ? kc : POST;
    }
    __syncthreads();
    const int kc = cnt;
    for (int rI = tid; rI < POST; rI += 256) {
        float o0 = 0.f, o1 = 0.f, o2 = 0.f, o3 = 0.f, o4 = 0.f;
        if (rI < kc) {
            int i = kept[rI];
            const float* tb = topb + ((size_t)n * PRE + i) * 4;
            o0 = tb[0]; o1 = tb[1]; o2 = tb[2]; o3 = tb[3]; o4 = sval[i];
        }
        float* op = out + ((size_t)n * POST + rI) * 5;
        op[0] = o0; op[1] = o1; op[2] = o2; op[3] = o3; op[4] = o4;
    }
}

extern "C" void kernel_launch(void* const* d_in, const int* in_sizes, int n_in,
                              void* d_out, int out_size, void* d_ws, size_t ws_size,
                              hipStream_t stream) {
    const float* obj    = (const float*)d_in[0];   // [8,15,100,100]
    const float* deltas = (const float*)d_in[1];   // [8,60,100,100]
    float* out = (float*)d_out;                    // [8,1000,5]
    char* ws = (char*)d_ws;

    unsigned*            cnt   = (unsigned*)(ws + WS_CNT);
    unsigned long long*  cand  = (unsigned long long*)(ws + WS_CAND);
    unsigned*            phist = (unsigned*)(ws + WS_PHIST);
    float*               topb  = (float*)(ws + WS_TOPB);
    float*               tops  = (float*)(ws + WS_TOPS);
    unsigned long long*  mask  = (unsigned long long*)(ws + WS_MASK);

    k_hist       <<<dim3(NIMG, 8), 1024, 0, stream>>>(obj, phist, cnt);
    k_compact    <<<dim3(NIMG, 8), 1024, 0, stream>>>(obj, phist, cand, cnt);
    k_sort_decode<<<NIMG, 1024, 0, stream>>>(cand, cnt, deltas, topb, tops);
    k_iou        <<<dim3(NIMG, 63), 256, 0, stream>>>(topb, mask);
    k_nms_out    <<<NIMG, 256, 0, stream>>>(topb, tops, mask, out);
}